// Round 3
// baseline (1025.416 us; speedup 1.0000x reference)
//
#include <hip/hip_runtime.h>
#include <hip/hip_bf16.h>
#include <math.h>

#define BB 64
#define T 128
#define DD 768
#define H 256
#define JJ 128
#define NSPAN 8256
#define KTOP 256
#define SCAP 1024
#define MARGIN 0.03f

typedef __attribute__((ext_vector_type(8))) short bf16x8;
typedef __attribute__((ext_vector_type(4))) float f32x4;

__device__ inline unsigned short bfrne(float x) {
    unsigned u = __float_as_uint(x);
    return (unsigned short)((u + 0x7FFFu + ((u >> 16) & 1u)) >> 16);
}

__device__ inline unsigned pk2(float x, float y) {
    float2 f; f.x = x; f.y = y;
    __hip_bfloat162 h = __float22bfloat162_rn(f);
    return *reinterpret_cast<unsigned*>(&h);
}

// 16-lane butterfly-sum step on the VALU pipe (no LDS): v += dpp_move(v).
template<int CTRL>
__device__ __forceinline__ float dpp_add16(float v) {
    return v + __int_as_float(__builtin_amdgcn_update_dpp(
        0, __float_as_int(v), CTRL, 0xF, 0xF, true));
}

// ---------------------------------------------------------------------------
// Kernel 1 (fused prep+proj): blocks 0..511 = proj GEMM v5; 512 = idx tables;
// 513..768 = W_s1 bf16 fragment pack; 769..832 = injection projection.
// R13 proj redesign (R12 was still LDS-pipe-bound at 42% VALU: 3 b128 reads
// per 32 FMA-instr = 144 LDS-cy demand per 64 VALU-cy across 4 SIMDs):
//   - wave owns 8 rows x 256 cols (lane: 4 cols). X values are wave-uniform
//     -> all-lane-uniform float4 global loads into registers (one L1
//     transaction each), double-buffered one full 8-k tile ahead. X is OFF
//     the LDS pipe entirely.
//   - W tile [8k][512] in LDS (reg-staged double-buffer). Per k per wave:
//     ONE contiguous ds_read_b128 (1KB, conflict-free) feeding 32 FMA-instr.
//   - per wave-tile: 96 read + 48 write LDS-cy vs 512 VALU-cy -> ~VALU-bound.
//   - k accumulation order 0..767 identical to previous version -> AE bitwise
//     unchanged.
// ---------------------------------------------------------------------------
__global__ __launch_bounds__(256, 2) void prep_proj_kernel(
    const float* __restrict__ X,
    const float* __restrict__ Wa, const float* __restrict__ ba,
    const float* __restrict__ Wb, const float* __restrict__ bb,
    float* __restrict__ AE,
    int* __restrict__ s_idx, int* __restrict__ e_idx,
    const float* __restrict__ W1, unsigned short* __restrict__ Wpk,
    const float* __restrict__ tie, const float* __restrict__ Winj,
    const float* __restrict__ binj, float* __restrict__ injv)
{
    const int blk = blockIdx.x;
    const int t = threadIdx.x;

    if (blk >= 512) {
        const int pblk = blk - 512;
        if (pblk == 0) {
            if (t < T) {
                int s = t;
                int start = s * T - (s * (s - 1)) / 2;
                int len = T - s;
                for (int i = 0; i < len; ++i) {
                    s_idx[start + i] = s;
                    e_idx[start + i] = s + i;
                }
            }
        } else if (pblk <= 256) {
            int idx = (pblk - 1) * 256 + t;   // 65536 total
            int j  = idx & 7;
            int l  = (idx >> 3) & 63;
            int kc = (idx >> 9) & 7;
            int ct = idx >> 12;
            int k = kc * 32 + (l >> 4) * 8 + j;
            int n = ct * 16 + (l & 15);
            Wpk[idx] = bfrne(W1[k * 256 + n]);
        } else {
            int b = pblk - 257;
            __shared__ float tb[JJ];
            if (t < JJ) tb[t] = tie[b * JJ + t];
            __syncthreads();
            float a = binj[t];
            for (int j = 0; j < JJ; ++j)
                a = fmaf(tb[j], Winj[j * H + t], a);
            injv[b * H + t] = a;
        }
        return;
    }

    // ---- proj part: blk 0..511 -> 16 rows x 512 cols per block ----
    const int m0   = blk * 16;
    const int w    = t >> 6;        // wave 0..3
    const int lane = t & 63;
    const int rg   = w >> 1;        // row group 0/1
    const int hf   = w & 1;         // col half 0/1 (0=start/Wa, 1=end/Wb)
    const int r0   = m0 + rg * 8;   // wave's first row
    const int cl   = lane * 4;      // lane's col within half

    __shared__ __align__(16) float Wt[2][8][512];

    float4 wreg[4];
    float4 xC[16], xN[16];
    float4 acc[8];

    // wave's 4 staging slots: j = w*4+i -> k-row j>>1, half j&1
    auto stageW_load = [&](int tileIdx) {
#pragma unroll
        for (int i = 0; i < 4; ++i) {
            const int j  = w * 4 + i;
            const int kr = j >> 1, jh = j & 1;
            const float* src = (jh ? Wb : Wa) + (size_t)(tileIdx * 8 + kr) * 256 + cl;
            wreg[i] = *(const float4*)src;
        }
    };
    auto stageW_write = [&](float (*dst)[512]) {
#pragma unroll
        for (int i = 0; i < 4; ++i) {
            const int j  = w * 4 + i;
            const int kr = j >> 1, jh = j & 1;
            *(float4*)&dst[kr][jh * 256 + cl] = wreg[i];
        }
    };
    auto loadX = [&](float4 (&xr)[16], int tileIdx) {
        const int kk = tileIdx * 8;
#pragma unroll
        for (int r = 0; r < 8; ++r) {
            const float* xp = &X[(size_t)(r0 + r) * DD + kk];
            xr[r * 2]     = *(const float4*)&xp[0];
            xr[r * 2 + 1] = *(const float4*)&xp[4];
        }
    };
    auto compute8 = [&](const float4 (&xr)[16], const float* wb) {
#pragma unroll
        for (int kq = 0; kq < 8; ++kq) {
            const float4 wv = *(const float4*)(wb + kq * 512);
#pragma unroll
            for (int r = 0; r < 8; ++r) {
                const float4 xv4 = xr[r * 2 + (kq >> 2)];
                const float xv = (kq & 3) == 0 ? xv4.x
                               : (kq & 3) == 1 ? xv4.y
                               : (kq & 3) == 2 ? xv4.z : xv4.w;
                acc[r].x = fmaf(xv, wv.x, acc[r].x);
                acc[r].y = fmaf(xv, wv.y, acc[r].y);
                acc[r].z = fmaf(xv, wv.z, acc[r].z);
                acc[r].w = fmaf(xv, wv.w, acc[r].w);
            }
        }
    };

    const float* w0 = &Wt[0][0][hf * 256 + cl];
    const float* w1 = &Wt[1][0][hf * 256 + cl];

#pragma unroll
    for (int r = 0; r < 8; ++r) { acc[r].x = 0.f; acc[r].y = 0.f; acc[r].z = 0.f; acc[r].w = 0.f; }

    // prologue: stage tile 0
    stageW_load(0);
    loadX(xC, 0);
    stageW_write(Wt[0]);
    __syncthreads();

    for (int tile = 0; tile < 96; tile += 2) {
        // even sub-tile: compute tile (buf 0, xC); prep tile+1
        stageW_load(tile + 1);
        loadX(xN, tile + 1);
        compute8(xC, w0);
        stageW_write(Wt[1]);
        __syncthreads();
        // odd sub-tile: compute tile+1 (buf 1, xN); prep tile+2
        const bool more = (tile + 2) < 96;
        if (more) { stageW_load(tile + 2); loadX(xC, tile + 2); }
        compute8(xN, w1);
        if (more) stageW_write(Wt[0]);
        __syncthreads();
    }

    const float* bsel = hf ? bb : ba;
    const float4 bq = *(const float4*)&bsel[cl];
#pragma unroll
    for (int r = 0; r < 8; ++r) {
        float4 o;
        o.x = acc[r].x + bq.x; o.y = acc[r].y + bq.y;
        o.z = acc[r].z + bq.z; o.w = acc[r].w + bq.w;
        *(float4*)&AE[(size_t)(r0 + r) * 512 + hf * 256 + cl] = o;
    }
}

// ---------------------------------------------------------------------------
// Kernel 2: approx scorer — software-pipelined tiles, 512 blocks x 512
// threads, XCD-local batch mapping. DPP layer-2 reduction + deep idx
// prefetch (R11, proven).
// ---------------------------------------------------------------------------
__global__ __launch_bounds__(512, 4) void approx_kernel(
    const float* __restrict__ AE,
    const unsigned short* __restrict__ Wpk,
    const float* __restrict__ bs1, const float* __restrict__ Ws2,
    const float* __restrict__ bs2g,
    const int* __restrict__ s_idx, const int* __restrict__ e_idx,
    const int* __restrict__ maskp,
    float* __restrict__ scores)
{
    const int bid   = blockIdx.x;       // 0..511
    const int r     = bid & 7;
    const int q     = bid >> 3;         // 0..63
    const int g     = q >> 3;
    const int chunk = q & 7;
    const int b     = g * 8 + r;
    const int tile0 = chunk * 65;
    const int tcnt  = (516 - tile0 < 65) ? (516 - tile0) : 65;

    __shared__ __align__(16) unsigned short rshf[2][8][64][8];  // 16 KB
    __shared__ float pslice[2][8][16];                          // 1 KB

    const int t      = threadIdx.x;
    const int w      = t >> 6;
    const int lane   = t & 63;
    const int lrow16 = lane & 15;
    const int quad   = lane >> 4;

    // held B fragments: ct = 2w + c (read once per kernel)
    bf16x8 bfr[2][8];
    float b1c[2], w2c[2];
#pragma unroll
    for (int c = 0; c < 2; ++c) {
#pragma unroll
        for (int kc = 0; kc < 8; ++kc)
            bfr[c][kc] = *(const bf16x8*)&Wpk[((((2 * w + c) * 8 + kc) * 64) + lane) * 8];
        int col = (2 * w + c) * 16 + lrow16;
        b1c[c] = bs1[col];
        w2c[c] = Ws2[col];
    }
    const float bs2v = bs2g[0];

    const float* Abase = AE + (size_t)b * T * 512;
    const int sp   = t >> 5;
    const int km   = t & 31;
    const int kc_s = km >> 2;
    const int q_s  = km & 3;
    const int slot = (q_s * 16 + sp + kc_s) & 63;

    // prologue: stage tile0 into buffer 0
    {
        int n = tile0 * 16 + sp;
        int s = s_idx[n], e = e_idx[n];
        const float* Ar = Abase + (size_t)s * 512 + km * 8;
        const float* Er = Abase + (size_t)e * 512 + 256 + km * 8;
        float4 a0 = *(const float4*)&Ar[0];
        float4 a1 = *(const float4*)&Ar[4];
        float4 e0 = *(const float4*)&Er[0];
        float4 e1 = *(const float4*)&Er[4];
        uint4 v;
        v.x = pk2(fmaxf(a0.x + e0.x, 0.f), fmaxf(a0.y + e0.y, 0.f));
        v.y = pk2(fmaxf(a0.z + e0.z, 0.f), fmaxf(a0.w + e0.w, 0.f));
        v.z = pk2(fmaxf(a1.x + e1.x, 0.f), fmaxf(a1.y + e1.y, 0.f));
        v.w = pk2(fmaxf(a1.z + e1.z, 0.f), fmaxf(a1.w + e1.w, 0.f));
        *(uint4*)&rshf[0][kc_s][slot][0] = v;
    }
    // index prefetch for tile0+1
    int s_nx = 0, e_nx = 0;
    if (tcnt > 1) {
        int n = (tile0 + 1) * 16 + sp;
        s_nx = s_idx[n]; e_nx = e_idx[n];
    }
    __syncthreads();

    for (int tt = 0; tt < tcnt; ++tt) {
        const int cur = tt & 1;
        float4 a0, a1, e0, e1;
        const bool pf = (tt + 1 < tcnt);
        if (pf) {
            const float* Ar = Abase + (size_t)s_nx * 512 + km * 8;
            const float* Er = Abase + (size_t)e_nx * 512 + 256 + km * 8;
            a0 = *(const float4*)&Ar[0];
            a1 = *(const float4*)&Ar[4];
            e0 = *(const float4*)&Er[0];
            e1 = *(const float4*)&Er[4];
        }
        if (tt + 2 < tcnt) {
            int n = (tile0 + tt + 2) * 16 + sp;
            s_nx = s_idx[n]; e_nx = e_idx[n];
        }
        f32x4 acc0 = {0.f, 0.f, 0.f, 0.f};
        f32x4 acc1 = {0.f, 0.f, 0.f, 0.f};
#pragma unroll
        for (int kc = 0; kc < 8; ++kc) {
            bf16x8 a = *(const bf16x8*)&rshf[cur][kc][(lane + kc) & 63][0];
            acc0 = __builtin_amdgcn_mfma_f32_16x16x32_bf16(a, bfr[0][kc], acc0, 0, 0, 0);
            acc1 = __builtin_amdgcn_mfma_f32_16x16x32_bf16(a, bfr[1][kc], acc1, 0, 0, 0);
        }
        float ps[4];
#pragma unroll
        for (int rr = 0; rr < 4; ++rr)
            ps[rr] = fmaxf(acc0[rr] + b1c[0], 0.f) * w2c[0]
                   + fmaxf(acc1[rr] + b1c[1], 0.f) * w2c[1];
        // 16-lane butterfly sum on the VALU pipe (DPP), no LDS traffic
#pragma unroll
        for (int rr = 0; rr < 4; ++rr) {
            float v = ps[rr];
            v = dpp_add16<0xB1>(v);    // xor1 (quad_perm)
            v = dpp_add16<0x4E>(v);    // xor2 (quad_perm)
            v = dpp_add16<0x141>(v);   // ^7 within 8 (row_half_mirror)
            v = dpp_add16<0x140>(v);   // ^15 within 16 (row_mirror)
            ps[rr] = v;
        }
        if (lrow16 == 0) {
            float4 v; v.x = ps[0]; v.y = ps[1]; v.z = ps[2]; v.w = ps[3];
            *(float4*)&pslice[cur][w][quad * 4] = v;
        }
        if (pf) {
            uint4 v;
            v.x = pk2(fmaxf(a0.x + e0.x, 0.f), fmaxf(a0.y + e0.y, 0.f));
            v.y = pk2(fmaxf(a0.z + e0.z, 0.f), fmaxf(a0.w + e0.w, 0.f));
            v.z = pk2(fmaxf(a1.x + e1.x, 0.f), fmaxf(a1.y + e1.y, 0.f));
            v.w = pk2(fmaxf(a1.z + e1.z, 0.f), fmaxf(a1.w + e1.w, 0.f));
            *(uint4*)&rshf[cur ^ 1][kc_s][slot][0] = v;
        }
        __syncthreads();
        if (t < 16) {
            int n = (tile0 + tt) * 16 + t;
            float sc = bs2v;
#pragma unroll
            for (int ww = 0; ww < 8; ++ww) sc += pslice[cur][ww][t];
            int s = s_idx[n], e = e_idx[n];
            bool m = (maskp[b * T + s] != 0) && (maskp[b * T + e] != 0);
            scores[(size_t)b * NSPAN + n] = m ? sc : -INFINITY;
        }
    }
}

// ---------------------------------------------------------------------------
// Kernel 3: shortlist select — byte radix, 1024 threads (compaction 33->9 chunks)
// ---------------------------------------------------------------------------
__global__ __launch_bounds__(1024) void select_kernel(
    const float* __restrict__ scores,
    int* __restrict__ shortlist, int* __restrict__ slcnt)
{
    const int b = blockIdx.x;
    const int t = threadIdx.x;
    __shared__ unsigned su[NSPAN];
    __shared__ int hist[256];
    __shared__ unsigned s_prefix;
    __shared__ int s_remaining;
    __shared__ int wave_keep[16];

    const float* sc = scores + (size_t)b * NSPAN;
    for (int i = t; i < NSPAN; i += 1024) {
        unsigned ub = __float_as_uint(sc[i]);
        su[i] = (ub & 0x80000000u) ? ~ub : (ub | 0x80000000u);
    }
    __syncthreads();

    unsigned prefix = 0;
    int remaining = KTOP;
    for (int d = 3; d >= 0; --d) {
        if (t < 256) hist[t] = 0;
        __syncthreads();
        const int sh = d * 8;
        for (int i = t; i < NSPAN; i += 1024) {
            unsigned u = su[i];
            bool match = (d == 3) || ((u >> (sh + 8)) == (prefix >> (sh + 8)));
            if (match) atomicAdd(&hist[(u >> sh) & 255], 1);
        }
        __syncthreads();
        if (t == 0) {
            int acc = 0, v = 255;
            for (; v > 0; --v) {
                int h = hist[v];
                if (acc + h >= remaining) break;
                acc += h;
            }
            s_prefix = prefix | ((unsigned)v << sh);
            s_remaining = remaining - acc;
        }
        __syncthreads();
        prefix = s_prefix;
        remaining = s_remaining;
        __syncthreads();
    }

    unsigned ub = (prefix & 0x80000000u) ? (prefix & 0x7FFFFFFFu) : ~prefix;
    float kthf = __uint_as_float(ub);
    float tau = kthf - MARGIN;
    unsigned tb = __float_as_uint(tau);
    unsigned ktau = (tb & 0x80000000u) ? ~tb : (tb | 0x80000000u);

    const int wid = t >> 6, lane = t & 63;
    int base = 0;
    const unsigned long long ltmask = (1ull << lane) - 1ull;
    for (int c0 = 0; c0 < NSPAN; c0 += 1024) {
        int n = c0 + t;
        bool keep = (n < NSPAN) && (su[n] >= ktau);
        unsigned long long bk = __ballot(keep);
        int before = __popcll(bk & ltmask);
        if (lane == 0) wave_keep[wid] = __popcll(bk);
        __syncthreads();
        int kb = base;
        for (int wv = 0; wv < wid; ++wv) kb += wave_keep[wv];
        if (keep) {
            int pos = kb + before;
            if (pos < SCAP) shortlist[b * SCAP + pos] = n;
        }
        for (int wv = 0; wv < 16; ++wv) base += wave_keep[wv];
        __syncthreads();
    }
    if (t == 0) slcnt[b] = base < SCAP ? base : SCAP;
}

// ---------------------------------------------------------------------------
// Kernel 4: exact fp32 scorer, 512 threads/block (unchanged)
// ---------------------------------------------------------------------------
__global__ __launch_bounds__(512) void exact_kernel(
    const float* __restrict__ AE,
    const float* __restrict__ Ws1, const float* __restrict__ bs1,
    const float* __restrict__ Ws2, const float* __restrict__ bs2g,
    const int* __restrict__ s_idx, const int* __restrict__ e_idx,
    const int* __restrict__ shortlist, const int* __restrict__ slcnt,
    float* __restrict__ scores)
{
    const int b  = blockIdx.y;
    const int n0 = blockIdx.x * 64;
    const int cntb = slcnt[b];
    if (n0 >= cntb) return;

    __shared__ float rsh[64][36];
    __shared__ float Ws[32][260];
    __shared__ int   ss[64], se[64], nn[64];

    const int t = threadIdx.x;
    if (t < 64) {
        int row = n0 + t;
        int n = 0;
        if (row < cntb) n = shortlist[b * SCAP + row];
        nn[t] = (row < cntb) ? n : -1;
        ss[t] = s_idx[n]; se[t] = e_idx[n];
    }
    __syncthreads();

    const int tx = t & 31;
    const int ty = t >> 5;
    float acc[4][8];
#pragma unroll
    for (int i = 0; i < 4; ++i)
#pragma unroll
        for (int j = 0; j < 8; ++j) acc[i][j] = 0.f;

    const float* Abase = AE + (size_t)b * T * 512;

    for (int kk = 0; kk < 256; kk += 32) {
        __syncthreads();
        {
            int row = t >> 4, q4 = (t & 15) * 4;
#pragma unroll
            for (int q = 0; q < 4; ++q)
                *(float4*)&Ws[row][q4 + q * 64] =
                    *(const float4*)&Ws1[(size_t)(kk + row) * 256 + q4 + q * 64];
        }
        {
            int sp = t >> 3, k4 = (t & 7) * 4;
            const float* Ar = Abase + (size_t)ss[sp] * 512 + kk + k4;
            const float* Er = Abase + (size_t)se[sp] * 512 + 256 + kk + k4;
            float4 a = *(const float4*)Ar;
            float4 e = *(const float4*)Er;
            float4 v;
            v.x = fmaxf(a.x + e.x, 0.f); v.y = fmaxf(a.y + e.y, 0.f);
            v.z = fmaxf(a.z + e.z, 0.f); v.w = fmaxf(a.w + e.w, 0.f);
            *(float4*)&rsh[sp][k4] = v;
        }
        __syncthreads();
#pragma unroll
        for (int k4 = 0; k4 < 32; k4 += 4) {
            float w[4][8];
#pragma unroll
            for (int kq = 0; kq < 4; ++kq) {
                float4 w0 = *(const float4*)&Ws[k4 + kq][tx * 4];
                float4 w1 = *(const float4*)&Ws[k4 + kq][128 + tx * 4];
                w[kq][0] = w0.x; w[kq][1] = w0.y; w[kq][2] = w0.z; w[kq][3] = w0.w;
                w[kq][4] = w1.x; w[kq][5] = w1.y; w[kq][6] = w1.z; w[kq][7] = w1.w;
            }
#pragma unroll
            for (int i = 0; i < 4; ++i) {
                float4 rv = *(const float4*)&rsh[ty * 4 + i][k4];
                float rq[4] = {rv.x, rv.y, rv.z, rv.w};
#pragma unroll
                for (int kq = 0; kq < 4; ++kq)
#pragma unroll
                    for (int j = 0; j < 8; ++j)
                        acc[i][j] = fmaf(rq[kq], w[kq][j], acc[i][j]);
            }
        }
    }

    float b1[8], w2[8];
#pragma unroll
    for (int j = 0; j < 8; ++j) {
        int c = (j < 4) ? (tx * 4 + j) : (128 + tx * 4 + j - 4);
        b1[j] = bs1[c];
        w2[j] = Ws2[c];
    }
    const float bs2v = bs2g[0];
#pragma unroll
    for (int i = 0; i < 4; ++i) {
        int r = ty * 4 + i;
        float p = 0.f;
#pragma unroll
        for (int j = 0; j < 8; ++j)
            p += fmaxf(acc[i][j] + b1[j], 0.f) * w2[j];
#pragma unroll
        for (int off = 16; off > 0; off >>= 1)
            p += __shfl_down(p, off, 32);
        if (tx == 0) {
            int n = nn[r];
            if (n >= 0)
                scores[(size_t)b * NSPAN + n] = p + bs2v;
        }
    }
}

// ---------------------------------------------------------------------------
// Kernel 5: top-K over the shortlist — 1024 threads (single compaction chunk)
// ---------------------------------------------------------------------------
__global__ __launch_bounds__(1024) void topk_kernel(
    const float* __restrict__ scores,
    const int* __restrict__ shortlist, const int* __restrict__ slcnt,
    int* __restrict__ top_idx, float* __restrict__ top_scores)
{
    const int b = blockIdx.x;
    const int t = threadIdx.x;
    const int cnt = slcnt[b];

    __shared__ unsigned su[SCAP];
    __shared__ int sn[SCAP];
    __shared__ int hist[256];
    __shared__ unsigned s_prefix;
    __shared__ int s_remaining;
    __shared__ int wave_eq[16], wave_keep[16];

    for (int i = t; i < cnt; i += 1024) {
        int n = shortlist[b * SCAP + i];
        unsigned ub = __float_as_uint(scores[(size_t)b * NSPAN + n]);
        su[i] = (ub & 0x80000000u) ? ~ub : (ub | 0x80000000u);
        sn[i] = n;
    }
    __syncthreads();

    unsigned prefix = 0;
    int remaining = KTOP;
    for (int d = 3; d >= 0; --d) {
        if (t < 256) hist[t] = 0;
        __syncthreads();
        const int sh = d * 8;
        for (int i = t; i < cnt; i += 1024) {
            unsigned u = su[i];
            bool match = (d == 3) || ((u >> (sh + 8)) == (prefix >> (sh + 8)));
            if (match) atomicAdd(&hist[(u >> sh) & 255], 1);
        }
        __syncthreads();
        if (t == 0) {
            int acc = 0, v = 255;
            for (; v > 0; --v) {
                int h = hist[v];
                if (acc + h >= remaining) break;
                acc += h;
            }
            s_prefix = prefix | ((unsigned)v << sh);
            s_remaining = remaining - acc;
        }
        __syncthreads();
        prefix = s_prefix;
        remaining = s_remaining;
        __syncthreads();
    }
    const unsigned v = prefix;
    const int need_eq = remaining;

    const int wid = t >> 6, lane = t & 63;
    int base_eq = 0, base_keep = 0;
    const unsigned long long ltmask = (1ull << lane) - 1ull;
    for (int c0 = 0; c0 < cnt; c0 += 1024) {
        int i = c0 + t;
        bool valid = i < cnt;
        unsigned u = valid ? su[i] : 0u;
        bool eq = valid && (u == v);
        bool gt = valid && (u > v);
        unsigned long long beq = __ballot(eq);
        int eq_before = __popcll(beq & ltmask);
        if (lane == 0) wave_eq[wid] = __popcll(beq);
        __syncthreads();
        int eqb = base_eq;
        for (int w = 0; w < wid; ++w) eqb += wave_eq[w];
        int eq_rank = eqb + eq_before;
        bool keep = gt || (eq && (eq_rank < need_eq));
        unsigned long long bk = __ballot(keep);
        int keep_before = __popcll(bk & ltmask);
        if (lane == 0) wave_keep[wid] = __popcll(bk);
        __syncthreads();
        int kb = base_keep;
        for (int w = 0; w < wid; ++w) kb += wave_keep[w];
        if (keep) {
            int pos = kb + keep_before;
            top_idx[b * KTOP + pos] = sn[i];
            unsigned fb = (u & 0x80000000u) ? (u & 0x7FFFFFFFu) : ~u;
            float f = __uint_as_float(fb);
            top_scores[b * KTOP + pos] = isinf(f) ? -1.0f : f;
        }
        for (int w = 0; w < 16; ++w) { base_eq += wave_eq[w]; base_keep += wave_keep[w]; }
        __syncthreads();
    }
}

// ---------------------------------------------------------------------------
// Kernel 6: final head (unchanged)
// ---------------------------------------------------------------------------
__global__ __launch_bounds__(256) void final_kernel(
    const float* __restrict__ AE,
    const int* __restrict__ s_idx, const int* __restrict__ e_idx,
    const int* __restrict__ maskp,
    const int* __restrict__ top_idx, const float* __restrict__ top_scores,
    const float* __restrict__ injv,
    const float* __restrict__ Wsec, const float* __restrict__ bsec,
    const float* __restrict__ Wpred, const float* __restrict__ bpredg,
    float* __restrict__ out)
{
    const int b = blockIdx.x >> 2;
    const int k0 = (blockIdx.x & 3) * 64;

    __shared__ float sh[64][36];
    __shared__ float Ws[32][260];
    __shared__ int ss[64], se[64];
    __shared__ float msk[64], tsc[64];

    const int t = threadIdx.x;
    if (t < 64) {
        int kidx = k0 + t;
        int n = top_idx[b * KTOP + kidx];
        int s = s_idx[n], e = e_idx[n];
        ss[t] = s; se[t] = e;
        msk[t] = (maskp[b * T + s] != 0 && maskp[b * T + e] != 0) ? 1.f : 0.f;
        tsc[t] = top_scores[b * KTOP + kidx];
    }
    __syncthreads();

    const int tx = t & 31;
    const int ty = t >> 5;
    float acc[8][8];
#pragma unroll
    for (int i = 0; i < 8; ++i)
#pragma unroll
        for (int j = 0; j < 8; ++j) acc[i][j] = 0.f;

    const float* Abase = AE + (size_t)b * T * 512;

    for (int kk = 0; kk < 256; kk += 32) {
        __syncthreads();
        {
            int c4 = (t & 63) * 4, r0 = t >> 6;
#pragma unroll
            for (int r8 = 0; r8 < 8; ++r8) {
                int row = r0 + r8 * 4;
                *(float4*)&Ws[row][c4] =
                    *(const float4*)&Wsec[(size_t)(kk + row) * 256 + c4];
            }
        }
        {
            int sp = t >> 2, k8 = (t & 3) * 8;
            const float* Ar = Abase + (size_t)ss[sp] * 512 + kk + k8;
            const float* Er = Abase + (size_t)se[sp] * 512 + 256 + kk + k8;
#pragma unroll
            for (int q = 0; q < 2; ++q) {
                float4 a = *(const float4*)&Ar[q * 4];
                float4 e = *(const float4*)&Er[q * 4];
                float4 v;
                v.x = a.x + e.x; v.y = a.y + e.y; v.z = a.z + e.z; v.w = a.w + e.w;
                *(float4*)&sh[sp][k8 + q * 4] = v;
            }
        }
        __syncthreads();
#pragma unroll
        for (int k4 = 0; k4 < 32; k4 += 4) {
            float w[4][8];
#pragma unroll
            for (int kq = 0; kq < 4; ++kq) {
                float4 w0 = *(const float4*)&Ws[k4 + kq][tx * 4];
                float4 w1 = *(const float4*)&Ws[k4 + kq][128 + tx * 4];
                w[kq][0] = w0.x; w[kq][1] = w0.y; w[kq][2] = w0.z; w[kq][3] = w0.w;
                w[kq][4] = w1.x; w[kq][5] = w1.y; w[kq][6] = w1.z; w[kq][7] = w1.w;
            }
#pragma unroll
            for (int i = 0; i < 8; ++i) {
                float4 rv = *(const float4*)&sh[ty * 8 + i][k4];
                float rq[4] = {rv.x, rv.y, rv.z, rv.w};
#pragma unroll
                for (int kq = 0; kq < 4; ++kq)
#pragma unroll
                    for (int j = 0; j < 8; ++j)
                        acc[i][j] = fmaf(rq[kq], w[kq][j], acc[i][j]);
            }
        }
    }

    float bsec_r[8], wpred_r[8], injr[8];
#pragma unroll
    for (int j = 0; j < 8; ++j) {
        int c = (j < 4) ? (tx * 4 + j) : (128 + tx * 4 + j - 4);
        bsec_r[j] = bsec[c];
        wpred_r[j] = Wpred[c];
        injr[j] = injv[b * H + c];
    }
    const float bp = bpredg[0];
#pragma unroll
    for (int i = 0; i < 8; ++i) {
        int r = ty * 8 + i;
        float p = 0.f;
#pragma unroll
        for (int j = 0; j < 8; ++j) {
            float sec = acc[i][j] + bsec_r[j];
            p += fmaxf(injr[j] + sec, 0.f) * wpred_r[j];
        }
#pragma unroll
        for (int off = 16; off > 0; off >>= 1)
            p += __shfl_down(p, off, 32);
        if (tx == 0) {
            float logit = p + bp + tsc[r];
            float prob = (1.f / (1.f + expf(-logit))) * msk[r];
            out[b * KTOP + k0 + r] = prob;
        }
    }
}

// ---------------------------------------------------------------------------
extern "C" void kernel_launch(void* const* d_in, const int* in_sizes, int n_in,
                              void* d_out, int out_size, void* d_ws, size_t ws_size,
                              hipStream_t stream) {
    const float* inputs  = (const float*)d_in[0];
    const int*   imask   = (const int*)d_in[1];
    const float* tie     = (const float*)d_in[2];
    const float* W_start = (const float*)d_in[3];
    const float* b_start = (const float*)d_in[4];
    const float* W_end   = (const float*)d_in[5];
    const float* b_end   = (const float*)d_in[6];
    const float* W_s1    = (const float*)d_in[7];
    const float* b_s1    = (const float*)d_in[8];
    const float* W_s2    = (const float*)d_in[9];
    const float* b_s2    = (const float*)d_in[10];
    const float* W_inj   = (const float*)d_in[11];
    const float* b_inj   = (const float*)d_in[12];
    const float* W_sec   = (const float*)d_in[13];
    const float* b_sec   = (const float*)d_in[14];
    const float* W_pred  = (const float*)d_in[15];
    const float* b_pred  = (const float*)d_in[16];
    float* out = (float*)d_out;

    float* AE         = (float*)d_ws;
    float* scores     = AE + (size_t)BB * T * 512;
    int*   s_idx      = (int*)(scores + (size_t)BB * NSPAN);
    int*   e_idx      = s_idx + NSPAN;
    int*   top_idx    = e_idx + NSPAN;
    float* top_scores = (float*)(top_idx + BB * KTOP);
    float* injv       = top_scores + BB * KTOP;
    unsigned short* Wpk = (unsigned short*)(injv + BB * H);
    int*   shortlist  = (int*)(Wpk + 65536);
    int*   slcnt      = shortlist + BB * SCAP;

    prep_proj_kernel<<<833, 256, 0, stream>>>(inputs, W_start, b_start, W_end, b_end, AE,
                                              s_idx, e_idx, W_s1, Wpk,
                                              tie, W_inj, b_inj, injv);
    approx_kernel<<<512, 512, 0, stream>>>(AE, Wpk, b_s1, W_s2, b_s2,
                                           s_idx, e_idx, imask, scores);
    select_kernel<<<BB, 1024, 0, stream>>>(scores, shortlist, slcnt);
    exact_kernel<<<dim3(16, BB), 512, 0, stream>>>(AE, W_s1, b_s1, W_s2, b_s2,
                                                   s_idx, e_idx, shortlist, slcnt, scores);
    topk_kernel<<<BB, 1024, 0, stream>>>(scores, shortlist, slcnt, top_idx, top_scores);
    final_kernel<<<BB * 4, 256, 0, stream>>>(AE, s_idx, e_idx, imask, top_idx, top_scores,
                                             injv, W_sec, b_sec, W_pred, b_pred, out);
}

// Round 4
// 500.473 us; speedup vs baseline: 2.0489x; 2.0489x over previous
//
#include <hip/hip_runtime.h>
#include <hip/hip_bf16.h>
#include <math.h>

#define BB 64
#define T 128
#define DD 768
#define H 256
#define JJ 128
#define NSPAN 8256
#define KTOP 256
#define SCAP 1024
#define MARGIN 0.03f

typedef __attribute__((ext_vector_type(8))) short bf16x8;
typedef __attribute__((ext_vector_type(4))) float f32x4;

__device__ inline unsigned short bfrne(float x) {
    unsigned u = __float_as_uint(x);
    return (unsigned short)((u + 0x7FFFu + ((u >> 16) & 1u)) >> 16);
}

__device__ inline unsigned pk2(float x, float y) {
    float2 f; f.x = x; f.y = y;
    __hip_bfloat162 h = __float22bfloat162_rn(f);
    return *reinterpret_cast<unsigned*>(&h);
}

// 16-lane butterfly-sum step on the VALU pipe (no LDS): v += dpp_move(v).
template<int CTRL>
__device__ __forceinline__ float dpp_add16(float v) {
    return v + __int_as_float(__builtin_amdgcn_update_dpp(
        0, __float_as_int(v), CTRL, 0xF, 0xF, true));
}

// ---------------------------------------------------------------------------
// Kernel 1 (fused prep+proj): blocks 0..255 = proj GEMM v6; 256 = idx tables;
// 257..512 = W_s1 bf16 fragment pack; 513..576 = injection projection.
// R14 proj (R13 spilled: 180 VGPR live under a (256,2) cap -> 1.6GB scratch;
// reverted to the R12 LDS scheme but with 8x8 per-thread blocking to halve
// LDS bytes/FMA, which was R12's 42%-VALU bottleneck):
//   - tile 128x128, 256 blocks, 256 thr; per-thread 8 rows x 8 cols.
//   - X in LDS [row][36] with k-granule XOR swizzle (granule = kb ^ (row>>3&7)):
//     compute reads are 4-addr broadcasts on 4 distinct bank-quads
//     (quad = r8 + (kb^ty) mod 8), staged writes 2-way (free). 16B-aligned.
//   - W keeps the proven [32][140] + wro swizzle (2-way reads/writes).
//   - per 4k per wave: 16 b128 reads vs 512 VALU-cy of FMA -> ~1.2-1.5x LDS
//     demand across 4 SIMDs (was 2.25x) -> VALU-bound-ish.
//   - NO min-waves launch_bounds cap: let compiler take ~150 VGPR, no spill.
//   - k accumulation order 0..767 per output unchanged -> AE bitwise same.
// ---------------------------------------------------------------------------
__global__ __launch_bounds__(256) void prep_proj_kernel(
    const float* __restrict__ X,
    const float* __restrict__ Wa, const float* __restrict__ ba,
    const float* __restrict__ Wb, const float* __restrict__ bb,
    float* __restrict__ AE,
    int* __restrict__ s_idx, int* __restrict__ e_idx,
    const float* __restrict__ W1, unsigned short* __restrict__ Wpk,
    const float* __restrict__ tie, const float* __restrict__ Winj,
    const float* __restrict__ binj, float* __restrict__ injv)
{
    const int blk = blockIdx.x;
    const int t = threadIdx.x;

    if (blk >= 256) {
        const int pblk = blk - 256;
        if (pblk == 0) {
            if (t < T) {
                int s = t;
                int start = s * T - (s * (s - 1)) / 2;
                int len = T - s;
                for (int i = 0; i < len; ++i) {
                    s_idx[start + i] = s;
                    e_idx[start + i] = s + i;
                }
            }
        } else if (pblk <= 256) {
            int idx = (pblk - 1) * 256 + t;   // 65536 total
            int j  = idx & 7;
            int l  = (idx >> 3) & 63;
            int kc = (idx >> 9) & 7;
            int ct = idx >> 12;
            int k = kc * 32 + (l >> 4) * 8 + j;
            int n = ct * 16 + (l & 15);
            Wpk[idx] = bfrne(W1[k * 256 + n]);
        } else {
            int b = pblk - 257;
            __shared__ float tb[JJ];
            if (t < JJ) tb[t] = tie[b * JJ + t];
            __syncthreads();
            float a = binj[t];
            for (int j = 0; j < JJ; ++j)
                a = fmaf(tb[j], Winj[j * H + t], a);
            injv[b * H + t] = a;
        }
        return;
    }

    // ---- proj part: blk 0..255 -> (px 0..63, cb 0..3), tile 128x128 ----
    const int px = blk & 63;
    const int cb = blk >> 6;
    const int m0 = px * 128;
    const float* W    = (cb < 2) ? Wa : Wb;
    const float* bias = (cb < 2) ? ba : bb;
    const int wc0 = (cb & 1) * 128;
    const int oc0 = (cb < 2) ? wc0 : (256 + wc0);

    // Xs[row][36]: k-granule g (4 floats) of row stored at ((g ^ (row>>3&7))<<2)
    // Wl[k][140]: col-block wi at wro(wi) = wi*8 + ((wi>>2)<<2)
    __shared__ __align__(16) float Xs[128 * 36];
    __shared__ __align__(16) float Wl[32 * 140];

    const int tx = t & 15;
    const int ty = t >> 4;                        // 0..15
    const int ty7 = ty & 7;                       // swizzle key for X reads
    const int wro = tx * 8 + ((tx >> 2) << 2);    // W read/write swizzled offset

    // X staging: 2 threads per row, 16 floats each (granules xh,xh+2,xh+4,xh+6)
    const int xrow = t >> 1;
    const int xh   = t & 1;
    const int xsw  = (xrow >> 3) & 7;
    // W staging: same as R2
    const int wrow = t >> 4;
    const int wi   = t & 15;

    float4 xg[4], w0r[2], w1r[2];
    {
        const float* xp = &X[(size_t)(m0 + xrow) * DD];
#pragma unroll
        for (int q = 0; q < 4; ++q)
            xg[q] = *(const float4*)&xp[(2 * q + xh) * 4];
        const float* wp0 = &W[(size_t)wrow * 256 + wc0 + wi * 8];
        w0r[0] = *(const float4*)&wp0[0]; w0r[1] = *(const float4*)&wp0[4];
        const float* wp1 = &W[(size_t)(wrow + 16) * 256 + wc0 + wi * 8];
        w1r[0] = *(const float4*)&wp1[0]; w1r[1] = *(const float4*)&wp1[4];
    }

    float acc[8][8];
#pragma unroll
    for (int i = 0; i < 8; ++i)
#pragma unroll
        for (int j = 0; j < 8; ++j) acc[i][j] = 0.f;

    for (int it = 0; it < 24; ++it) {
        __syncthreads();
        // X: 4 swizzled b128 writes (granule kb = 2q+xh)
#pragma unroll
        for (int q = 0; q < 4; ++q) {
            const int kb = 2 * q + xh;
            *(float4*)&Xs[xrow * 36 + ((kb ^ xsw) << 2)] = xg[q];
        }
        // W: swizzled row writes (proven R2 pattern)
        *(float4*)&Wl[wrow * 140 + wro]            = w0r[0];
        *(float4*)&Wl[wrow * 140 + wro + 4]        = w0r[1];
        *(float4*)&Wl[(wrow + 16) * 140 + wro]     = w1r[0];
        *(float4*)&Wl[(wrow + 16) * 140 + wro + 4] = w1r[1];
        __syncthreads();
        if (it + 1 < 24) {
            const int kk = (it + 1) * 32;
            const float* xp = &X[(size_t)(m0 + xrow) * DD + kk];
#pragma unroll
            for (int q = 0; q < 4; ++q)
                xg[q] = *(const float4*)&xp[(2 * q + xh) * 4];
            const float* wp0 = &W[(size_t)(kk + wrow) * 256 + wc0 + wi * 8];
            w0r[0] = *(const float4*)&wp0[0]; w0r[1] = *(const float4*)&wp0[4];
            const float* wp1 = &W[(size_t)(kk + wrow + 16) * 256 + wc0 + wi * 8];
            w1r[0] = *(const float4*)&wp1[0]; w1r[1] = *(const float4*)&wp1[4];
        }
#pragma unroll
        for (int kb = 0; kb < 8; ++kb) {
            // X: 8 rows (ty*8..+7) x 4k — broadcast b128, 4 distinct bank-quads
            float4 xv[8];
#pragma unroll
            for (int r8 = 0; r8 < 8; ++r8)
                xv[r8] = *(const float4*)&Xs[(ty * 8 + r8) * 36 + ((kb ^ ty7) << 2)];
#pragma unroll
            for (int j = 0; j < 4; ++j) {
                const int k = kb * 4 + j;
                float4 wv0 = *(const float4*)&Wl[k * 140 + wro];
                float4 wv1 = *(const float4*)&Wl[k * 140 + wro + 4];
                float wq[8] = {wv0.x, wv0.y, wv0.z, wv0.w, wv1.x, wv1.y, wv1.z, wv1.w};
#pragma unroll
                for (int r8 = 0; r8 < 8; ++r8) {
                    const float xv1 = j == 0 ? xv[r8].x : j == 1 ? xv[r8].y
                                    : j == 2 ? xv[r8].z : xv[r8].w;
#pragma unroll
                    for (int c = 0; c < 8; ++c)
                        acc[r8][c] = fmaf(xv1, wq[c], acc[r8][c]);
                }
            }
        }
    }

    float bq[8];
#pragma unroll
    for (int j = 0; j < 8; ++j) bq[j] = bias[wc0 + tx * 8 + j];
#pragma unroll
    for (int r8 = 0; r8 < 8; ++r8) {
        const size_t row = m0 + ty * 8 + r8;
        float4 o0, o1;
        o0.x = acc[r8][0] + bq[0]; o0.y = acc[r8][1] + bq[1];
        o0.z = acc[r8][2] + bq[2]; o0.w = acc[r8][3] + bq[3];
        o1.x = acc[r8][4] + bq[4]; o1.y = acc[r8][5] + bq[5];
        o1.z = acc[r8][6] + bq[6]; o1.w = acc[r8][7] + bq[7];
        *(float4*)&AE[row * 512 + oc0 + tx * 8]     = o0;
        *(float4*)&AE[row * 512 + oc0 + tx * 8 + 4] = o1;
    }
}

// ---------------------------------------------------------------------------
// Kernel 2: approx scorer — software-pipelined tiles, 512 blocks x 512
// threads, XCD-local batch mapping. DPP layer-2 reduction + deep idx
// prefetch (R11, proven).
// ---------------------------------------------------------------------------
__global__ __launch_bounds__(512, 4) void approx_kernel(
    const float* __restrict__ AE,
    const unsigned short* __restrict__ Wpk,
    const float* __restrict__ bs1, const float* __restrict__ Ws2,
    const float* __restrict__ bs2g,
    const int* __restrict__ s_idx, const int* __restrict__ e_idx,
    const int* __restrict__ maskp,
    float* __restrict__ scores)
{
    const int bid   = blockIdx.x;       // 0..511
    const int r     = bid & 7;
    const int q     = bid >> 3;         // 0..63
    const int g     = q >> 3;
    const int chunk = q & 7;
    const int b     = g * 8 + r;
    const int tile0 = chunk * 65;
    const int tcnt  = (516 - tile0 < 65) ? (516 - tile0) : 65;

    __shared__ __align__(16) unsigned short rshf[2][8][64][8];  // 16 KB
    __shared__ float pslice[2][8][16];                          // 1 KB

    const int t      = threadIdx.x;
    const int w      = t >> 6;
    const int lane   = t & 63;
    const int lrow16 = lane & 15;
    const int quad   = lane >> 4;

    // held B fragments: ct = 2w + c (read once per kernel)
    bf16x8 bfr[2][8];
    float b1c[2], w2c[2];
#pragma unroll
    for (int c = 0; c < 2; ++c) {
#pragma unroll
        for (int kc = 0; kc < 8; ++kc)
            bfr[c][kc] = *(const bf16x8*)&Wpk[((((2 * w + c) * 8 + kc) * 64) + lane) * 8];
        int col = (2 * w + c) * 16 + lrow16;
        b1c[c] = bs1[col];
        w2c[c] = Ws2[col];
    }
    const float bs2v = bs2g[0];

    const float* Abase = AE + (size_t)b * T * 512;
    const int sp   = t >> 5;
    const int km   = t & 31;
    const int kc_s = km >> 2;
    const int q_s  = km & 3;
    const int slot = (q_s * 16 + sp + kc_s) & 63;

    // prologue: stage tile0 into buffer 0
    {
        int n = tile0 * 16 + sp;
        int s = s_idx[n], e = e_idx[n];
        const float* Ar = Abase + (size_t)s * 512 + km * 8;
        const float* Er = Abase + (size_t)e * 512 + 256 + km * 8;
        float4 a0 = *(const float4*)&Ar[0];
        float4 a1 = *(const float4*)&Ar[4];
        float4 e0 = *(const float4*)&Er[0];
        float4 e1 = *(const float4*)&Er[4];
        uint4 v;
        v.x = pk2(fmaxf(a0.x + e0.x, 0.f), fmaxf(a0.y + e0.y, 0.f));
        v.y = pk2(fmaxf(a0.z + e0.z, 0.f), fmaxf(a0.w + e0.w, 0.f));
        v.z = pk2(fmaxf(a1.x + e1.x, 0.f), fmaxf(a1.y + e1.y, 0.f));
        v.w = pk2(fmaxf(a1.z + e1.z, 0.f), fmaxf(a1.w + e1.w, 0.f));
        *(uint4*)&rshf[0][kc_s][slot][0] = v;
    }
    // index prefetch for tile0+1
    int s_nx = 0, e_nx = 0;
    if (tcnt > 1) {
        int n = (tile0 + 1) * 16 + sp;
        s_nx = s_idx[n]; e_nx = e_idx[n];
    }
    __syncthreads();

    for (int tt = 0; tt < tcnt; ++tt) {
        const int cur = tt & 1;
        float4 a0, a1, e0, e1;
        const bool pf = (tt + 1 < tcnt);
        if (pf) {
            const float* Ar = Abase + (size_t)s_nx * 512 + km * 8;
            const float* Er = Abase + (size_t)e_nx * 512 + 256 + km * 8;
            a0 = *(const float4*)&Ar[0];
            a1 = *(const float4*)&Ar[4];
            e0 = *(const float4*)&Er[0];
            e1 = *(const float4*)&Er[4];
        }
        if (tt + 2 < tcnt) {
            int n = (tile0 + tt + 2) * 16 + sp;
            s_nx = s_idx[n]; e_nx = e_idx[n];
        }
        f32x4 acc0 = {0.f, 0.f, 0.f, 0.f};
        f32x4 acc1 = {0.f, 0.f, 0.f, 0.f};
#pragma unroll
        for (int kc = 0; kc < 8; ++kc) {
            bf16x8 a = *(const bf16x8*)&rshf[cur][kc][(lane + kc) & 63][0];
            acc0 = __builtin_amdgcn_mfma_f32_16x16x32_bf16(a, bfr[0][kc], acc0, 0, 0, 0);
            acc1 = __builtin_amdgcn_mfma_f32_16x16x32_bf16(a, bfr[1][kc], acc1, 0, 0, 0);
        }
        float ps[4];
#pragma unroll
        for (int rr = 0; rr < 4; ++rr)
            ps[rr] = fmaxf(acc0[rr] + b1c[0], 0.f) * w2c[0]
                   + fmaxf(acc1[rr] + b1c[1], 0.f) * w2c[1];
        // 16-lane butterfly sum on the VALU pipe (DPP), no LDS traffic
#pragma unroll
        for (int rr = 0; rr < 4; ++rr) {
            float v = ps[rr];
            v = dpp_add16<0xB1>(v);    // xor1 (quad_perm)
            v = dpp_add16<0x4E>(v);    // xor2 (quad_perm)
            v = dpp_add16<0x141>(v);   // ^7 within 8 (row_half_mirror)
            v = dpp_add16<0x140>(v);   // ^15 within 16 (row_mirror)
            ps[rr] = v;
        }
        if (lrow16 == 0) {
            float4 v; v.x = ps[0]; v.y = ps[1]; v.z = ps[2]; v.w = ps[3];
            *(float4*)&pslice[cur][w][quad * 4] = v;
        }
        if (pf) {
            uint4 v;
            v.x = pk2(fmaxf(a0.x + e0.x, 0.f), fmaxf(a0.y + e0.y, 0.f));
            v.y = pk2(fmaxf(a0.z + e0.z, 0.f), fmaxf(a0.w + e0.w, 0.f));
            v.z = pk2(fmaxf(a1.x + e1.x, 0.f), fmaxf(a1.y + e1.y, 0.f));
            v.w = pk2(fmaxf(a1.z + e1.z, 0.f), fmaxf(a1.w + e1.w, 0.f));
            *(uint4*)&rshf[cur ^ 1][kc_s][slot][0] = v;
        }
        __syncthreads();
        if (t < 16) {
            int n = (tile0 + tt) * 16 + t;
            float sc = bs2v;
#pragma unroll
            for (int ww = 0; ww < 8; ++ww) sc += pslice[cur][ww][t];
            int s = s_idx[n], e = e_idx[n];
            bool m = (maskp[b * T + s] != 0) && (maskp[b * T + e] != 0);
            scores[(size_t)b * NSPAN + n] = m ? sc : -INFINITY;
        }
    }
}

// ---------------------------------------------------------------------------
// Kernel 3: shortlist select — byte radix, 1024 threads (compaction 33->9 chunks)
// ---------------------------------------------------------------------------
__global__ __launch_bounds__(1024) void select_kernel(
    const float* __restrict__ scores,
    int* __restrict__ shortlist, int* __restrict__ slcnt)
{
    const int b = blockIdx.x;
    const int t = threadIdx.x;
    __shared__ unsigned su[NSPAN];
    __shared__ int hist[256];
    __shared__ unsigned s_prefix;
    __shared__ int s_remaining;
    __shared__ int wave_keep[16];

    const float* sc = scores + (size_t)b * NSPAN;
    for (int i = t; i < NSPAN; i += 1024) {
        unsigned ub = __float_as_uint(sc[i]);
        su[i] = (ub & 0x80000000u) ? ~ub : (ub | 0x80000000u);
    }
    __syncthreads();

    unsigned prefix = 0;
    int remaining = KTOP;
    for (int d = 3; d >= 0; --d) {
        if (t < 256) hist[t] = 0;
        __syncthreads();
        const int sh = d * 8;
        for (int i = t; i < NSPAN; i += 1024) {
            unsigned u = su[i];
            bool match = (d == 3) || ((u >> (sh + 8)) == (prefix >> (sh + 8)));
            if (match) atomicAdd(&hist[(u >> sh) & 255], 1);
        }
        __syncthreads();
        if (t == 0) {
            int acc = 0, v = 255;
            for (; v > 0; --v) {
                int h = hist[v];
                if (acc + h >= remaining) break;
                acc += h;
            }
            s_prefix = prefix | ((unsigned)v << sh);
            s_remaining = remaining - acc;
        }
        __syncthreads();
        prefix = s_prefix;
        remaining = s_remaining;
        __syncthreads();
    }

    unsigned ub = (prefix & 0x80000000u) ? (prefix & 0x7FFFFFFFu) : ~prefix;
    float kthf = __uint_as_float(ub);
    float tau = kthf - MARGIN;
    unsigned tb = __float_as_uint(tau);
    unsigned ktau = (tb & 0x80000000u) ? ~tb : (tb | 0x80000000u);

    const int wid = t >> 6, lane = t & 63;
    int base = 0;
    const unsigned long long ltmask = (1ull << lane) - 1ull;
    for (int c0 = 0; c0 < NSPAN; c0 += 1024) {
        int n = c0 + t;
        bool keep = (n < NSPAN) && (su[n] >= ktau);
        unsigned long long bk = __ballot(keep);
        int before = __popcll(bk & ltmask);
        if (lane == 0) wave_keep[wid] = __popcll(bk);
        __syncthreads();
        int kb = base;
        for (int wv = 0; wv < wid; ++wv) kb += wave_keep[wv];
        if (keep) {
            int pos = kb + before;
            if (pos < SCAP) shortlist[b * SCAP + pos] = n;
        }
        for (int wv = 0; wv < 16; ++wv) base += wave_keep[wv];
        __syncthreads();
    }
    if (t == 0) slcnt[b] = base < SCAP ? base : SCAP;
}

// ---------------------------------------------------------------------------
// Kernel 4: exact fp32 scorer, 512 threads/block (unchanged)
// ---------------------------------------------------------------------------
__global__ __launch_bounds__(512) void exact_kernel(
    const float* __restrict__ AE,
    const float* __restrict__ Ws1, const float* __restrict__ bs1,
    const float* __restrict__ Ws2, const float* __restrict__ bs2g,
    const int* __restrict__ s_idx, const int* __restrict__ e_idx,
    const int* __restrict__ shortlist, const int* __restrict__ slcnt,
    float* __restrict__ scores)
{
    const int b  = blockIdx.y;
    const int n0 = blockIdx.x * 64;
    const int cntb = slcnt[b];
    if (n0 >= cntb) return;

    __shared__ float rsh[64][36];
    __shared__ float Ws[32][260];
    __shared__ int   ss[64], se[64], nn[64];

    const int t = threadIdx.x;
    if (t < 64) {
        int row = n0 + t;
        int n = 0;
        if (row < cntb) n = shortlist[b * SCAP + row];
        nn[t] = (row < cntb) ? n : -1;
        ss[t] = s_idx[n]; se[t] = e_idx[n];
    }
    __syncthreads();

    const int tx = t & 31;
    const int ty = t >> 5;
    float acc[4][8];
#pragma unroll
    for (int i = 0; i < 4; ++i)
#pragma unroll
        for (int j = 0; j < 8; ++j) acc[i][j] = 0.f;

    const float* Abase = AE + (size_t)b * T * 512;

    for (int kk = 0; kk < 256; kk += 32) {
        __syncthreads();
        {
            int row = t >> 4, q4 = (t & 15) * 4;
#pragma unroll
            for (int q = 0; q < 4; ++q)
                *(float4*)&Ws[row][q4 + q * 64] =
                    *(const float4*)&Ws1[(size_t)(kk + row) * 256 + q4 + q * 64];
        }
        {
            int sp = t >> 3, k4 = (t & 7) * 4;
            const float* Ar = Abase + (size_t)ss[sp] * 512 + kk + k4;
            const float* Er = Abase + (size_t)se[sp] * 512 + 256 + kk + k4;
            float4 a = *(const float4*)Ar;
            float4 e = *(const float4*)Er;
            float4 v;
            v.x = fmaxf(a.x + e.x, 0.f); v.y = fmaxf(a.y + e.y, 0.f);
            v.z = fmaxf(a.z + e.z, 0.f); v.w = fmaxf(a.w + e.w, 0.f);
            *(float4*)&rsh[sp][k4] = v;
        }
        __syncthreads();
#pragma unroll
        for (int k4 = 0; k4 < 32; k4 += 4) {
            float w[4][8];
#pragma unroll
            for (int kq = 0; kq < 4; ++kq) {
                float4 w0 = *(const float4*)&Ws[k4 + kq][tx * 4];
                float4 w1 = *(const float4*)&Ws[k4 + kq][128 + tx * 4];
                w[kq][0] = w0.x; w[kq][1] = w0.y; w[kq][2] = w0.z; w[kq][3] = w0.w;
                w[kq][4] = w1.x; w[kq][5] = w1.y; w[kq][6] = w1.z; w[kq][7] = w1.w;
            }
#pragma unroll
            for (int i = 0; i < 4; ++i) {
                float4 rv = *(const float4*)&rsh[ty * 4 + i][k4];
                float rq[4] = {rv.x, rv.y, rv.z, rv.w};
#pragma unroll
                for (int kq = 0; kq < 4; ++kq)
#pragma unroll
                    for (int j = 0; j < 8; ++j)
                        acc[i][j] = fmaf(rq[kq], w[kq][j], acc[i][j]);
            }
        }
    }

    float b1[8], w2[8];
#pragma unroll
    for (int j = 0; j < 8; ++j) {
        int c = (j < 4) ? (tx * 4 + j) : (128 + tx * 4 + j - 4);
        b1[j] = bs1[c];
        w2[j] = Ws2[c];
    }
    const float bs2v = bs2g[0];
#pragma unroll
    for (int i = 0; i < 4; ++i) {
        int r = ty * 4 + i;
        float p = 0.f;
#pragma unroll
        for (int j = 0; j < 8; ++j)
            p += fmaxf(acc[i][j] + b1[j], 0.f) * w2[j];
#pragma unroll
        for (int off = 16; off > 0; off >>= 1)
            p += __shfl_down(p, off, 32);
        if (tx == 0) {
            int n = nn[r];
            if (n >= 0)
                scores[(size_t)b * NSPAN + n] = p + bs2v;
        }
    }
}

// ---------------------------------------------------------------------------
// Kernel 5: top-K over the shortlist — 1024 threads (single compaction chunk)
// ---------------------------------------------------------------------------
__global__ __launch_bounds__(1024) void topk_kernel(
    const float* __restrict__ scores,
    const int* __restrict__ shortlist, const int* __restrict__ slcnt,
    int* __restrict__ top_idx, float* __restrict__ top_scores)
{
    const int b = blockIdx.x;
    const int t = threadIdx.x;
    const int cnt = slcnt[b];

    __shared__ unsigned su[SCAP];
    __shared__ int sn[SCAP];
    __shared__ int hist[256];
    __shared__ unsigned s_prefix;
    __shared__ int s_remaining;
    __shared__ int wave_eq[16], wave_keep[16];

    for (int i = t; i < cnt; i += 1024) {
        int n = shortlist[b * SCAP + i];
        unsigned ub = __float_as_uint(scores[(size_t)b * NSPAN + n]);
        su[i] = (ub & 0x80000000u) ? ~ub : (ub | 0x80000000u);
        sn[i] = n;
    }
    __syncthreads();

    unsigned prefix = 0;
    int remaining = KTOP;
    for (int d = 3; d >= 0; --d) {
        if (t < 256) hist[t] = 0;
        __syncthreads();
        const int sh = d * 8;
        for (int i = t; i < cnt; i += 1024) {
            unsigned u = su[i];
            bool match = (d == 3) || ((u >> (sh + 8)) == (prefix >> (sh + 8)));
            if (match) atomicAdd(&hist[(u >> sh) & 255], 1);
        }
        __syncthreads();
        if (t == 0) {
            int acc = 0, v = 255;
            for (; v > 0; --v) {
                int h = hist[v];
                if (acc + h >= remaining) break;
                acc += h;
            }
            s_prefix = prefix | ((unsigned)v << sh);
            s_remaining = remaining - acc;
        }
        __syncthreads();
        prefix = s_prefix;
        remaining = s_remaining;
        __syncthreads();
    }
    const unsigned v = prefix;
    const int need_eq = remaining;

    const int wid = t >> 6, lane = t & 63;
    int base_eq = 0, base_keep = 0;
    const unsigned long long ltmask = (1ull << lane) - 1ull;
    for (int c0 = 0; c0 < cnt; c0 += 1024) {
        int i = c0 + t;
        bool valid = i < cnt;
        unsigned u = valid ? su[i] : 0u;
        bool eq = valid && (u == v);
        bool gt = valid && (u > v);
        unsigned long long beq = __ballot(eq);
        int eq_before = __popcll(beq & ltmask);
        if (lane == 0) wave_eq[wid] = __popcll(beq);
        __syncthreads();
        int eqb = base_eq;
        for (int w = 0; w < wid; ++w) eqb += wave_eq[w];
        int eq_rank = eqb + eq_before;
        bool keep = gt || (eq && (eq_rank < need_eq));
        unsigned long long bk = __ballot(keep);
        int keep_before = __popcll(bk & ltmask);
        if (lane == 0) wave_keep[wid] = __popcll(bk);
        __syncthreads();
        int kb = base_keep;
        for (int w = 0; w < wid; ++w) kb += wave_keep[w];
        if (keep) {
            int pos = kb + keep_before;
            top_idx[b * KTOP + pos] = sn[i];
            unsigned fb = (u & 0x80000000u) ? (u & 0x7FFFFFFFu) : ~u;
            float f = __uint_as_float(fb);
            top_scores[b * KTOP + pos] = isinf(f) ? -1.0f : f;
        }
        for (int w = 0; w < 16; ++w) { base_eq += wave_eq[w]; base_keep += wave_keep[w]; }
        __syncthreads();
    }
}

// ---------------------------------------------------------------------------
// Kernel 6: final head (unchanged)
// ---------------------------------------------------------------------------
__global__ __launch_bounds__(256) void final_kernel(
    const float* __restrict__ AE,
    const int* __restrict__ s_idx, const int* __restrict__ e_idx,
    const int* __restrict__ maskp,
    const int* __restrict__ top_idx, const float* __restrict__ top_scores,
    const float* __restrict__ injv,
    const float* __restrict__ Wsec, const float* __restrict__ bsec,
    const float* __restrict__ Wpred, const float* __restrict__ bpredg,
    float* __restrict__ out)
{
    const int b = blockIdx.x >> 2;
    const int k0 = (blockIdx.x & 3) * 64;

    __shared__ float sh[64][36];
    __shared__ float Ws[32][260];
    __shared__ int ss[64], se[64];
    __shared__ float msk[64], tsc[64];

    const int t = threadIdx.x;
    if (t < 64) {
        int kidx = k0 + t;
        int n = top_idx[b * KTOP + kidx];
        int s = s_idx[n], e = e_idx[n];
        ss[t] = s; se[t] = e;
        msk[t] = (maskp[b * T + s] != 0 && maskp[b * T + e] != 0) ? 1.f : 0.f;
        tsc[t] = top_scores[b * KTOP + kidx];
    }
    __syncthreads();

    const int tx = t & 31;
    const int ty = t >> 5;
    float acc[8][8];
#pragma unroll
    for (int i = 0; i < 8; ++i)
#pragma unroll
        for (int j = 0; j < 8; ++j) acc[i][j] = 0.f;

    const float* Abase = AE + (size_t)b * T * 512;

    for (int kk = 0; kk < 256; kk += 32) {
        __syncthreads();
        {
            int c4 = (t & 63) * 4, r0 = t >> 6;
#pragma unroll
            for (int r8 = 0; r8 < 8; ++r8) {
                int row = r0 + r8 * 4;
                *(float4*)&Ws[row][c4] =
                    *(const float4*)&Wsec[(size_t)(kk + row) * 256 + c4];
            }
        }
        {
            int sp = t >> 2, k8 = (t & 3) * 8;
            const float* Ar = Abase + (size_t)ss[sp] * 512 + kk + k8;
            const float* Er = Abase + (size_t)se[sp] * 512 + 256 + kk + k8;
#pragma unroll
            for (int q = 0; q < 2; ++q) {
                float4 a = *(const float4*)&Ar[q * 4];
                float4 e = *(const float4*)&Er[q * 4];
                float4 v;
                v.x = a.x + e.x; v.y = a.y + e.y; v.z = a.z + e.z; v.w = a.w + e.w;
                *(float4*)&sh[sp][k8 + q * 4] = v;
            }
        }
        __syncthreads();
#pragma unroll
        for (int k4 = 0; k4 < 32; k4 += 4) {
            float w[4][8];
#pragma unroll
            for (int kq = 0; kq < 4; ++kq) {
                float4 w0 = *(const float4*)&Ws[k4 + kq][tx * 4];
                float4 w1 = *(const float4*)&Ws[k4 + kq][128 + tx * 4];
                w[kq][0] = w0.x; w[kq][1] = w0.y; w[kq][2] = w0.z; w[kq][3] = w0.w;
                w[kq][4] = w1.x; w[kq][5] = w1.y; w[kq][6] = w1.z; w[kq][7] = w1.w;
            }
#pragma unroll
            for (int i = 0; i < 8; ++i) {
                float4 rv = *(const float4*)&sh[ty * 8 + i][k4];
                float rq[4] = {rv.x, rv.y, rv.z, rv.w};
#pragma unroll
                for (int kq = 0; kq < 4; ++kq)
#pragma unroll
                    for (int j = 0; j < 8; ++j)
                        acc[i][j] = fmaf(rq[kq], w[kq][j], acc[i][j]);
            }
        }
    }

    float bsec_r[8], wpred_r[8], injr[8];
#pragma unroll
    for (int j = 0; j < 8; ++j) {
        int c = (j < 4) ? (tx * 4 + j) : (128 + tx * 4 + j - 4);
        bsec_r[j] = bsec[c];
        wpred_r[j] = Wpred[c];
        injr[j] = injv[b * H + c];
    }
    const float bp = bpredg[0];
#pragma unroll
    for (int i = 0; i < 8; ++i) {
        int r = ty * 8 + i;
        float p = 0.f;
#pragma unroll
        for (int j = 0; j < 8; ++j) {
            float sec = acc[i][j] + bsec_r[j];
            p += fmaxf(injr[j] + sec, 0.f) * wpred_r[j];
        }
#pragma unroll
        for (int off = 16; off > 0; off >>= 1)
            p += __shfl_down(p, off, 32);
        if (tx == 0) {
            float logit = p + bp + tsc[r];
            float prob = (1.f / (1.f + expf(-logit))) * msk[r];
            out[b * KTOP + k0 + r] = prob;
        }
    }
}

// ---------------------------------------------------------------------------
extern "C" void kernel_launch(void* const* d_in, const int* in_sizes, int n_in,
                              void* d_out, int out_size, void* d_ws, size_t ws_size,
                              hipStream_t stream) {
    const float* inputs  = (const float*)d_in[0];
    const int*   imask   = (const int*)d_in[1];
    const float* tie     = (const float*)d_in[2];
    const float* W_start = (const float*)d_in[3];
    const float* b_start = (const float*)d_in[4];
    const float* W_end   = (const float*)d_in[5];
    const float* b_end   = (const float*)d_in[6];
    const float* W_s1    = (const float*)d_in[7];
    const float* b_s1    = (const float*)d_in[8];
    const float* W_s2    = (const float*)d_in[9];
    const float* b_s2    = (const float*)d_in[10];
    const float* W_inj   = (const float*)d_in[11];
    const float* b_inj   = (const float*)d_in[12];
    const float* W_sec   = (const float*)d_in[13];
    const float* b_sec   = (const float*)d_in[14];
    const float* W_pred  = (const float*)d_in[15];
    const float* b_pred  = (const float*)d_in[16];
    float* out = (float*)d_out;

    float* AE         = (float*)d_ws;
    float* scores     = AE + (size_t)BB * T * 512;
    int*   s_idx      = (int*)(scores + (size_t)BB * NSPAN);
    int*   e_idx      = s_idx + NSPAN;
    int*   top_idx    = e_idx + NSPAN;
    float* top_scores = (float*)(top_idx + BB * KTOP);
    float* injv       = top_scores + BB * KTOP;
    unsigned short* Wpk = (unsigned short*)(injv + BB * H);
    int*   shortlist  = (int*)(Wpk + 65536);
    int*   slcnt      = shortlist + BB * SCAP;

    prep_proj_kernel<<<577, 256, 0, stream>>>(inputs, W_start, b_start, W_end, b_end, AE,
                                              s_idx, e_idx, W_s1, Wpk,
                                              tie, W_inj, b_inj, injv);
    approx_kernel<<<512, 512, 0, stream>>>(AE, Wpk, b_s1, W_s2, b_s2,
                                           s_idx, e_idx, imask, scores);
    select_kernel<<<BB, 1024, 0, stream>>>(scores, shortlist, slcnt);
    exact_kernel<<<dim3(16, BB), 512, 0, stream>>>(AE, W_s1, b_s1, W_s2, b_s2,
                                                   s_idx, e_idx, shortlist, slcnt, scores);
    topk_kernel<<<BB, 1024, 0, stream>>>(scores, shortlist, slcnt, top_idx, top_scores);
    final_kernel<<<BB * 4, 256, 0, stream>>>(AE, s_idx, e_idx, imask, top_idx, top_scores,
                                             injv, W_sec, b_sec, W_pred, b_pred, out);
}

// Round 5
// 477.739 us; speedup vs baseline: 2.1464x; 1.0476x over previous
//
#include <hip/hip_runtime.h>
#include <hip/hip_bf16.h>
#include <math.h>

#define BB 64
#define T 128
#define DD 768
#define H 256
#define JJ 128
#define NSPAN 8256
#define KTOP 256
#define SCAP 1024
#define MARGIN 0.03f

typedef __attribute__((ext_vector_type(8))) short bf16x8;
typedef __attribute__((ext_vector_type(4))) float f32x4;

__device__ inline unsigned short bfrne(float x) {
    unsigned u = __float_as_uint(x);
    return (unsigned short)((u + 0x7FFFu + ((u >> 16) & 1u)) >> 16);
}

__device__ inline unsigned pk2(float x, float y) {
    float2 f; f.x = x; f.y = y;
    __hip_bfloat162 h = __float22bfloat162_rn(f);
    return *reinterpret_cast<unsigned*>(&h);
}

// 16-lane butterfly-sum step on the VALU pipe (no LDS): v += dpp_move(v).
template<int CTRL>
__device__ __forceinline__ float dpp_add16(float v) {
    return v + __int_as_float(__builtin_amdgcn_update_dpp(
        0, __float_as_int(v), CTRL, 0xF, 0xF, true));
}

// ---------------------------------------------------------------------------
// Kernel 1 (fused prep+proj): blocks 0..255 = proj GEMM v7; 256 = idx tables;
// 257..512 = W_s1 bf16 fragment pack; 513..576 = injection projection.
// R15 proj: ZERO-LDS register-blocked GEMM (R4 died of occupancy: 1 blk/CU,
// 1 wave/SIMD, barrier+ds_read latency exposed -> VALU 32%):
//   - tile 128x128, per-thread 8x8; X loads are wave-broadcast (4 addrs/instr,
//     L1-served), W loads 16 addrs/instr (L1/L2-served, shared by all waves
//     and all 64 px-blocks per cb).
//   - NO __shared__, NO __syncthreads: each wave fully independent. Explicit
//     A/B ping-pong prefetch at 4k granularity: 16 in-flight loads per 512
//     FMA-cycles covers ~200cy L2 latency within a single wave.
//   - VGPR budget: acc 64 + 4x8 float4 prefetch 128 + addr ~15 = ~205 < 256,
//     NO min-waves launch_bounds cap -> no spill (the R13 failure).
//   - VMEM totals: W 201MB + X 100MB from L2 (~6us at 34.5TB/s); HBM ~27MB.
//   - k accumulation order 0..767 unchanged -> AE bitwise identical.
// ---------------------------------------------------------------------------
__global__ __launch_bounds__(256) void prep_proj_kernel(
    const float* __restrict__ X,
    const float* __restrict__ Wa, const float* __restrict__ ba,
    const float* __restrict__ Wb, const float* __restrict__ bb,
    float* __restrict__ AE,
    int* __restrict__ s_idx, int* __restrict__ e_idx,
    const float* __restrict__ W1, unsigned short* __restrict__ Wpk,
    const float* __restrict__ tie, const float* __restrict__ Winj,
    const float* __restrict__ binj, float* __restrict__ injv)
{
    const int blk = blockIdx.x;
    const int t = threadIdx.x;

    if (blk >= 256) {
        const int pblk = blk - 256;
        if (pblk == 0) {
            if (t < T) {
                int s = t;
                int start = s * T - (s * (s - 1)) / 2;
                int len = T - s;
                for (int i = 0; i < len; ++i) {
                    s_idx[start + i] = s;
                    e_idx[start + i] = s + i;
                }
            }
        } else if (pblk <= 256) {
            int idx = (pblk - 1) * 256 + t;   // 65536 total
            int j  = idx & 7;
            int l  = (idx >> 3) & 63;
            int kc = (idx >> 9) & 7;
            int ct = idx >> 12;
            int k = kc * 32 + (l >> 4) * 8 + j;
            int n = ct * 16 + (l & 15);
            Wpk[idx] = bfrne(W1[k * 256 + n]);
        } else {
            int b = pblk - 257;
            __shared__ float tb[JJ];
            if (t < JJ) tb[t] = tie[b * JJ + t];
            __syncthreads();
            float a = binj[t];
            for (int j = 0; j < JJ; ++j)
                a = fmaf(tb[j], Winj[j * H + t], a);
            injv[b * H + t] = a;
        }
        return;
    }

    // ---- proj part: blk 0..255 -> (px 0..63, cb 0..3), tile 128x128 ----
    const int px = blk & 63;
    const int cb = blk >> 6;
    const int m0 = px * 128;
    const float* W    = (cb < 2) ? Wa : Wb;
    const float* bias = (cb < 2) ? ba : bb;
    const int wc0 = (cb & 1) * 128;
    const int oc0 = (cb < 2) ? wc0 : (256 + wc0);

    const int tx = t & 15;          // col block 0..15 (8 cols each)
    const int ty = t >> 4;          // row block 0..15 (8 rows each)
    const int r0 = m0 + ty * 8;
    const int c0 = wc0 + tx * 8;

    const float* Xb  = X + (size_t)r0 * DD;   // thread's 8 rows
    const float* Wc  = W + c0;                // thread's 8 cols

    float4 XA[8], WA[8], XB[8], WB[8];
    float acc[8][8];
#pragma unroll
    for (int i = 0; i < 8; ++i)
#pragma unroll
        for (int j = 0; j < 8; ++j) acc[i][j] = 0.f;

    // kb = 4-k granule index, 0..191
    auto loadX = [&](float4 (&xr)[8], int kb) {
        const int kk = kb * 4;
#pragma unroll
        for (int r = 0; r < 8; ++r)
            xr[r] = *(const float4*)&Xb[(size_t)r * DD + kk];
    };
    auto loadW = [&](float4 (&wr)[8], int kb) {
#pragma unroll
        for (int j = 0; j < 4; ++j) {
            const float* wp = &Wc[(size_t)(kb * 4 + j) * 256];
            wr[j * 2]     = *(const float4*)&wp[0];
            wr[j * 2 + 1] = *(const float4*)&wp[4];
        }
    };
    auto comp = [&](const float4 (&xr)[8], const float4 (&wr)[8]) {
#pragma unroll
        for (int j = 0; j < 4; ++j) {
            const float wq[8] = {wr[j*2].x, wr[j*2].y, wr[j*2].z, wr[j*2].w,
                                 wr[j*2+1].x, wr[j*2+1].y, wr[j*2+1].z, wr[j*2+1].w};
#pragma unroll
            for (int r = 0; r < 8; ++r) {
                const float xv = (j == 0) ? xr[r].x : (j == 1) ? xr[r].y
                               : (j == 2) ? xr[r].z : xr[r].w;
#pragma unroll
                for (int c = 0; c < 8; ++c)
                    acc[r][c] = fmaf(xv, wq[c], acc[r][c]);
            }
        }
    };

    loadX(XA, 0); loadW(WA, 0);
    for (int kb = 0; kb < 192; kb += 2) {
        loadX(XB, kb + 1); loadW(WB, kb + 1);   // prefetch odd granule
        comp(XA, WA);
        if (kb + 2 < 192) { loadX(XA, kb + 2); loadW(WA, kb + 2); }
        comp(XB, WB);
    }

    float bq[8];
#pragma unroll
    for (int j = 0; j < 8; ++j) bq[j] = bias[wc0 + tx * 8 + j];
#pragma unroll
    for (int r = 0; r < 8; ++r) {
        const size_t row = r0 + r;
        float4 o0, o1;
        o0.x = acc[r][0] + bq[0]; o0.y = acc[r][1] + bq[1];
        o0.z = acc[r][2] + bq[2]; o0.w = acc[r][3] + bq[3];
        o1.x = acc[r][4] + bq[4]; o1.y = acc[r][5] + bq[5];
        o1.z = acc[r][6] + bq[6]; o1.w = acc[r][7] + bq[7];
        *(float4*)&AE[row * 512 + oc0 + tx * 8]     = o0;
        *(float4*)&AE[row * 512 + oc0 + tx * 8 + 4] = o1;
    }
}

// ---------------------------------------------------------------------------
// Kernel 2: approx scorer — software-pipelined tiles, 512 blocks x 512
// threads, XCD-local batch mapping. DPP layer-2 reduction + deep idx
// prefetch (R11, proven).
// ---------------------------------------------------------------------------
__global__ __launch_bounds__(512, 4) void approx_kernel(
    const float* __restrict__ AE,
    const unsigned short* __restrict__ Wpk,
    const float* __restrict__ bs1, const float* __restrict__ Ws2,
    const float* __restrict__ bs2g,
    const int* __restrict__ s_idx, const int* __restrict__ e_idx,
    const int* __restrict__ maskp,
    float* __restrict__ scores)
{
    const int bid   = blockIdx.x;       // 0..511
    const int r     = bid & 7;
    const int q     = bid >> 3;         // 0..63
    const int g     = q >> 3;
    const int chunk = q & 7;
    const int b     = g * 8 + r;
    const int tile0 = chunk * 65;
    const int tcnt  = (516 - tile0 < 65) ? (516 - tile0) : 65;

    __shared__ __align__(16) unsigned short rshf[2][8][64][8];  // 16 KB
    __shared__ float pslice[2][8][16];                          // 1 KB

    const int t      = threadIdx.x;
    const int w      = t >> 6;
    const int lane   = t & 63;
    const int lrow16 = lane & 15;
    const int quad   = lane >> 4;

    // held B fragments: ct = 2w + c (read once per kernel)
    bf16x8 bfr[2][8];
    float b1c[2], w2c[2];
#pragma unroll
    for (int c = 0; c < 2; ++c) {
#pragma unroll
        for (int kc = 0; kc < 8; ++kc)
            bfr[c][kc] = *(const bf16x8*)&Wpk[((((2 * w + c) * 8 + kc) * 64) + lane) * 8];
        int col = (2 * w + c) * 16 + lrow16;
        b1c[c] = bs1[col];
        w2c[c] = Ws2[col];
    }
    const float bs2v = bs2g[0];

    const float* Abase = AE + (size_t)b * T * 512;
    const int sp   = t >> 5;
    const int km   = t & 31;
    const int kc_s = km >> 2;
    const int q_s  = km & 3;
    const int slot = (q_s * 16 + sp + kc_s) & 63;

    // prologue: stage tile0 into buffer 0
    {
        int n = tile0 * 16 + sp;
        int s = s_idx[n], e = e_idx[n];
        const float* Ar = Abase + (size_t)s * 512 + km * 8;
        const float* Er = Abase + (size_t)e * 512 + 256 + km * 8;
        float4 a0 = *(const float4*)&Ar[0];
        float4 a1 = *(const float4*)&Ar[4];
        float4 e0 = *(const float4*)&Er[0];
        float4 e1 = *(const float4*)&Er[4];
        uint4 v;
        v.x = pk2(fmaxf(a0.x + e0.x, 0.f), fmaxf(a0.y + e0.y, 0.f));
        v.y = pk2(fmaxf(a0.z + e0.z, 0.f), fmaxf(a0.w + e0.w, 0.f));
        v.z = pk2(fmaxf(a1.x + e1.x, 0.f), fmaxf(a1.y + e1.y, 0.f));
        v.w = pk2(fmaxf(a1.z + e1.z, 0.f), fmaxf(a1.w + e1.w, 0.f));
        *(uint4*)&rshf[0][kc_s][slot][0] = v;
    }
    // index prefetch for tile0+1
    int s_nx = 0, e_nx = 0;
    if (tcnt > 1) {
        int n = (tile0 + 1) * 16 + sp;
        s_nx = s_idx[n]; e_nx = e_idx[n];
    }
    __syncthreads();

    for (int tt = 0; tt < tcnt; ++tt) {
        const int cur = tt & 1;
        float4 a0, a1, e0, e1;
        const bool pf = (tt + 1 < tcnt);
        if (pf) {
            const float* Ar = Abase + (size_t)s_nx * 512 + km * 8;
            const float* Er = Abase + (size_t)e_nx * 512 + 256 + km * 8;
            a0 = *(const float4*)&Ar[0];
            a1 = *(const float4*)&Ar[4];
            e0 = *(const float4*)&Er[0];
            e1 = *(const float4*)&Er[4];
        }
        if (tt + 2 < tcnt) {
            int n = (tile0 + tt + 2) * 16 + sp;
            s_nx = s_idx[n]; e_nx = e_idx[n];
        }
        f32x4 acc0 = {0.f, 0.f, 0.f, 0.f};
        f32x4 acc1 = {0.f, 0.f, 0.f, 0.f};
#pragma unroll
        for (int kc = 0; kc < 8; ++kc) {
            bf16x8 a = *(const bf16x8*)&rshf[cur][kc][(lane + kc) & 63][0];
            acc0 = __builtin_amdgcn_mfma_f32_16x16x32_bf16(a, bfr[0][kc], acc0, 0, 0, 0);
            acc1 = __builtin_amdgcn_mfma_f32_16x16x32_bf16(a, bfr[1][kc], acc1, 0, 0, 0);
        }
        float ps[4];
#pragma unroll
        for (int rr = 0; rr < 4; ++rr)
            ps[rr] = fmaxf(acc0[rr] + b1c[0], 0.f) * w2c[0]
                   + fmaxf(acc1[rr] + b1c[1], 0.f) * w2c[1];
        // 16-lane butterfly sum on the VALU pipe (DPP), no LDS traffic
#pragma unroll
        for (int rr = 0; rr < 4; ++rr) {
            float v = ps[rr];
            v = dpp_add16<0xB1>(v);    // xor1 (quad_perm)
            v = dpp_add16<0x4E>(v);    // xor2 (quad_perm)
            v = dpp_add16<0x141>(v);   // ^7 within 8 (row_half_mirror)
            v = dpp_add16<0x140>(v);   // ^15 within 16 (row_mirror)
            ps[rr] = v;
        }
        if (lrow16 == 0) {
            float4 v; v.x = ps[0]; v.y = ps[1]; v.z = ps[2]; v.w = ps[3];
            *(float4*)&pslice[cur][w][quad * 4] = v;
        }
        if (pf) {
            uint4 v;
            v.x = pk2(fmaxf(a0.x + e0.x, 0.f), fmaxf(a0.y + e0.y, 0.f));
            v.y = pk2(fmaxf(a0.z + e0.z, 0.f), fmaxf(a0.w + e0.w, 0.f));
            v.z = pk2(fmaxf(a1.x + e1.x, 0.f), fmaxf(a1.y + e1.y, 0.f));
            v.w = pk2(fmaxf(a1.z + e1.z, 0.f), fmaxf(a1.w + e1.w, 0.f));
            *(uint4*)&rshf[cur ^ 1][kc_s][slot][0] = v;
        }
        __syncthreads();
        if (t < 16) {
            int n = (tile0 + tt) * 16 + t;
            float sc = bs2v;
#pragma unroll
            for (int ww = 0; ww < 8; ++ww) sc += pslice[cur][ww][t];
            int s = s_idx[n], e = e_idx[n];
            bool m = (maskp[b * T + s] != 0) && (maskp[b * T + e] != 0);
            scores[(size_t)b * NSPAN + n] = m ? sc : -INFINITY;
        }
    }
}

// ---------------------------------------------------------------------------
// Kernel 3: shortlist select — byte radix, 1024 threads (compaction 33->9 chunks)
// ---------------------------------------------------------------------------
__global__ __launch_bounds__(1024) void select_kernel(
    const float* __restrict__ scores,
    int* __restrict__ shortlist, int* __restrict__ slcnt)
{
    const int b = blockIdx.x;
    const int t = threadIdx.x;
    __shared__ unsigned su[NSPAN];
    __shared__ int hist[256];
    __shared__ unsigned s_prefix;
    __shared__ int s_remaining;
    __shared__ int wave_keep[16];

    const float* sc = scores + (size_t)b * NSPAN;
    for (int i = t; i < NSPAN; i += 1024) {
        unsigned ub = __float_as_uint(sc[i]);
        su[i] = (ub & 0x80000000u) ? ~ub : (ub | 0x80000000u);
    }
    __syncthreads();

    unsigned prefix = 0;
    int remaining = KTOP;
    for (int d = 3; d >= 0; --d) {
        if (t < 256) hist[t] = 0;
        __syncthreads();
        const int sh = d * 8;
        for (int i = t; i < NSPAN; i += 1024) {
            unsigned u = su[i];
            bool match = (d == 3) || ((u >> (sh + 8)) == (prefix >> (sh + 8)));
            if (match) atomicAdd(&hist[(u >> sh) & 255], 1);
        }
        __syncthreads();
        if (t == 0) {
            int acc = 0, v = 255;
            for (; v > 0; --v) {
                int h = hist[v];
                if (acc + h >= remaining) break;
                acc += h;
            }
            s_prefix = prefix | ((unsigned)v << sh);
            s_remaining = remaining - acc;
        }
        __syncthreads();
        prefix = s_prefix;
        remaining = s_remaining;
        __syncthreads();
    }

    unsigned ub = (prefix & 0x80000000u) ? (prefix & 0x7FFFFFFFu) : ~prefix;
    float kthf = __uint_as_float(ub);
    float tau = kthf - MARGIN;
    unsigned tb = __float_as_uint(tau);
    unsigned ktau = (tb & 0x80000000u) ? ~tb : (tb | 0x80000000u);

    const int wid = t >> 6, lane = t & 63;
    int base = 0;
    const unsigned long long ltmask = (1ull << lane) - 1ull;
    for (int c0 = 0; c0 < NSPAN; c0 += 1024) {
        int n = c0 + t;
        bool keep = (n < NSPAN) && (su[n] >= ktau);
        unsigned long long bk = __ballot(keep);
        int before = __popcll(bk & ltmask);
        if (lane == 0) wave_keep[wid] = __popcll(bk);
        __syncthreads();
        int kb = base;
        for (int wv = 0; wv < wid; ++wv) kb += wave_keep[wv];
        if (keep) {
            int pos = kb + before;
            if (pos < SCAP) shortlist[b * SCAP + pos] = n;
        }
        for (int wv = 0; wv < 16; ++wv) base += wave_keep[wv];
        __syncthreads();
    }
    if (t == 0) slcnt[b] = base < SCAP ? base : SCAP;
}

// ---------------------------------------------------------------------------
// Kernel 4: exact fp32 scorer, 512 threads/block (unchanged)
// ---------------------------------------------------------------------------
__global__ __launch_bounds__(512) void exact_kernel(
    const float* __restrict__ AE,
    const float* __restrict__ Ws1, const float* __restrict__ bs1,
    const float* __restrict__ Ws2, const float* __restrict__ bs2g,
    const int* __restrict__ s_idx, const int* __restrict__ e_idx,
    const int* __restrict__ shortlist, const int* __restrict__ slcnt,
    float* __restrict__ scores)
{
    const int b  = blockIdx.y;
    const int n0 = blockIdx.x * 64;
    const int cntb = slcnt[b];
    if (n0 >= cntb) return;

    __shared__ float rsh[64][36];
    __shared__ float Ws[32][260];
    __shared__ int   ss[64], se[64], nn[64];

    const int t = threadIdx.x;
    if (t < 64) {
        int row = n0 + t;
        int n = 0;
        if (row < cntb) n = shortlist[b * SCAP + row];
        nn[t] = (row < cntb) ? n : -1;
        ss[t] = s_idx[n]; se[t] = e_idx[n];
    }
    __syncthreads();

    const int tx = t & 31;
    const int ty = t >> 5;
    float acc[4][8];
#pragma unroll
    for (int i = 0; i < 4; ++i)
#pragma unroll
        for (int j = 0; j < 8; ++j) acc[i][j] = 0.f;

    const float* Abase = AE + (size_t)b * T * 512;

    for (int kk = 0; kk < 256; kk += 32) {
        __syncthreads();
        {
            int row = t >> 4, q4 = (t & 15) * 4;
#pragma unroll
            for (int q = 0; q < 4; ++q)
                *(float4*)&Ws[row][q4 + q * 64] =
                    *(const float4*)&Ws1[(size_t)(kk + row) * 256 + q4 + q * 64];
        }
        {
            int sp = t >> 3, k4 = (t & 7) * 4;
            const float* Ar = Abase + (size_t)ss[sp] * 512 + kk + k4;
            const float* Er = Abase + (size_t)se[sp] * 512 + 256 + kk + k4;
            float4 a = *(const float4*)Ar;
            float4 e = *(const float4*)Er;
            float4 v;
            v.x = fmaxf(a.x + e.x, 0.f); v.y = fmaxf(a.y + e.y, 0.f);
            v.z = fmaxf(a.z + e.z, 0.f); v.w = fmaxf(a.w + e.w, 0.f);
            *(float4*)&rsh[sp][k4] = v;
        }
        __syncthreads();
#pragma unroll
        for (int k4 = 0; k4 < 32; k4 += 4) {
            float w[4][8];
#pragma unroll
            for (int kq = 0; kq < 4; ++kq) {
                float4 w0 = *(const float4*)&Ws[k4 + kq][tx * 4];
                float4 w1 = *(const float4*)&Ws[k4 + kq][128 + tx * 4];
                w[kq][0] = w0.x; w[kq][1] = w0.y; w[kq][2] = w0.z; w[kq][3] = w0.w;
                w[kq][4] = w1.x; w[kq][5] = w1.y; w[kq][6] = w1.z; w[kq][7] = w1.w;
            }
#pragma unroll
            for (int i = 0; i < 4; ++i) {
                float4 rv = *(const float4*)&rsh[ty * 4 + i][k4];
                float rq[4] = {rv.x, rv.y, rv.z, rv.w};
#pragma unroll
                for (int kq = 0; kq < 4; ++kq)
#pragma unroll
                    for (int j = 0; j < 8; ++j)
                        acc[i][j] = fmaf(rq[kq], w[kq][j], acc[i][j]);
            }
        }
    }

    float b1[8], w2[8];
#pragma unroll
    for (int j = 0; j < 8; ++j) {
        int c = (j < 4) ? (tx * 4 + j) : (128 + tx * 4 + j - 4);
        b1[j] = bs1[c];
        w2[j] = Ws2[c];
    }
    const float bs2v = bs2g[0];
#pragma unroll
    for (int i = 0; i < 4; ++i) {
        int r = ty * 4 + i;
        float p = 0.f;
#pragma unroll
        for (int j = 0; j < 8; ++j)
            p += fmaxf(acc[i][j] + b1[j], 0.f) * w2[j];
#pragma unroll
        for (int off = 16; off > 0; off >>= 1)
            p += __shfl_down(p, off, 32);
        if (tx == 0) {
            int n = nn[r];
            if (n >= 0)
                scores[(size_t)b * NSPAN + n] = p + bs2v;
        }
    }
}

// ---------------------------------------------------------------------------
// Kernel 5: top-K over the shortlist — 1024 threads (single compaction chunk)
// ---------------------------------------------------------------------------
__global__ __launch_bounds__(1024) void topk_kernel(
    const float* __restrict__ scores,
    const int* __restrict__ shortlist, const int* __restrict__ slcnt,
    int* __restrict__ top_idx, float* __restrict__ top_scores)
{
    const int b = blockIdx.x;
    const int t = threadIdx.x;
    const int cnt = slcnt[b];

    __shared__ unsigned su[SCAP];
    __shared__ int sn[SCAP];
    __shared__ int hist[256];
    __shared__ unsigned s_prefix;
    __shared__ int s_remaining;
    __shared__ int wave_eq[16], wave_keep[16];

    for (int i = t; i < cnt; i += 1024) {
        int n = shortlist[b * SCAP + i];
        unsigned ub = __float_as_uint(scores[(size_t)b * NSPAN + n]);
        su[i] = (ub & 0x80000000u) ? ~ub : (ub | 0x80000000u);
        sn[i] = n;
    }
    __syncthreads();

    unsigned prefix = 0;
    int remaining = KTOP;
    for (int d = 3; d >= 0; --d) {
        if (t < 256) hist[t] = 0;
        __syncthreads();
        const int sh = d * 8;
        for (int i = t; i < cnt; i += 1024) {
            unsigned u = su[i];
            bool match = (d == 3) || ((u >> (sh + 8)) == (prefix >> (sh + 8)));
            if (match) atomicAdd(&hist[(u >> sh) & 255], 1);
        }
        __syncthreads();
        if (t == 0) {
            int acc = 0, v = 255;
            for (; v > 0; --v) {
                int h = hist[v];
                if (acc + h >= remaining) break;
                acc += h;
            }
            s_prefix = prefix | ((unsigned)v << sh);
            s_remaining = remaining - acc;
        }
        __syncthreads();
        prefix = s_prefix;
        remaining = s_remaining;
        __syncthreads();
    }
    const unsigned v = prefix;
    const int need_eq = remaining;

    const int wid = t >> 6, lane = t & 63;
    int base_eq = 0, base_keep = 0;
    const unsigned long long ltmask = (1ull << lane) - 1ull;
    for (int c0 = 0; c0 < cnt; c0 += 1024) {
        int i = c0 + t;
        bool valid = i < cnt;
        unsigned u = valid ? su[i] : 0u;
        bool eq = valid && (u == v);
        bool gt = valid && (u > v);
        unsigned long long beq = __ballot(eq);
        int eq_before = __popcll(beq & ltmask);
        if (lane == 0) wave_eq[wid] = __popcll(beq);
        __syncthreads();
        int eqb = base_eq;
        for (int w = 0; w < wid; ++w) eqb += wave_eq[w];
        int eq_rank = eqb + eq_before;
        bool keep = gt || (eq && (eq_rank < need_eq));
        unsigned long long bk = __ballot(keep);
        int keep_before = __popcll(bk & ltmask);
        if (lane == 0) wave_keep[wid] = __popcll(bk);
        __syncthreads();
        int kb = base_keep;
        for (int w = 0; w < wid; ++w) kb += wave_keep[w];
        if (keep) {
            int pos = kb + keep_before;
            top_idx[b * KTOP + pos] = sn[i];
            unsigned fb = (u & 0x80000000u) ? (u & 0x7FFFFFFFu) : ~u;
            float f = __uint_as_float(fb);
            top_scores[b * KTOP + pos] = isinf(f) ? -1.0f : f;
        }
        for (int w = 0; w < 16; ++w) { base_eq += wave_eq[w]; base_keep += wave_keep[w]; }
        __syncthreads();
    }
}

// ---------------------------------------------------------------------------
// Kernel 6: final head (unchanged)
// ---------------------------------------------------------------------------
__global__ __launch_bounds__(256) void final_kernel(
    const float* __restrict__ AE,
    const int* __restrict__ s_idx, const int* __restrict__ e_idx,
    const int* __restrict__ maskp,
    const int* __restrict__ top_idx, const float* __restrict__ top_scores,
    const float* __restrict__ injv,
    const float* __restrict__ Wsec, const float* __restrict__ bsec,
    const float* __restrict__ Wpred, const float* __restrict__ bpredg,
    float* __restrict__ out)
{
    const int b = blockIdx.x >> 2;
    const int k0 = (blockIdx.x & 3) * 64;

    __shared__ float sh[64][36];
    __shared__ float Ws[32][260];
    __shared__ int ss[64], se[64];
    __shared__ float msk[64], tsc[64];

    const int t = threadIdx.x;
    if (t < 64) {
        int kidx = k0 + t;
        int n = top_idx[b * KTOP + kidx];
        int s = s_idx[n], e = e_idx[n];
        ss[t] = s; se[t] = e;
        msk[t] = (maskp[b * T + s] != 0 && maskp[b * T + e] != 0) ? 1.f : 0.f;
        tsc[t] = top_scores[b * KTOP + kidx];
    }
    __syncthreads();

    const int tx = t & 31;
    const int ty = t >> 5;
    float acc[8][8];
#pragma unroll
    for (int i = 0; i < 8; ++i)
#pragma unroll
        for (int j = 0; j < 8; ++j) acc[i][j] = 0.f;

    const float* Abase = AE + (size_t)b * T * 512;

    for (int kk = 0; kk < 256; kk += 32) {
        __syncthreads();
        {
            int c4 = (t & 63) * 4, r0 = t >> 6;
#pragma unroll
            for (int r8 = 0; r8 < 8; ++r8) {
                int row = r0 + r8 * 4;
                *(float4*)&Ws[row][c4] =
                    *(const float4*)&Wsec[(size_t)(kk + row) * 256 + c4];
            }
        }
        {
            int sp = t >> 2, k8 = (t & 3) * 8;
            const float* Ar = Abase + (size_t)ss[sp] * 512 + kk + k8;
            const float* Er = Abase + (size_t)se[sp] * 512 + 256 + kk + k8;
#pragma unroll
            for (int q = 0; q < 2; ++q) {
                float4 a = *(const float4*)&Ar[q * 4];
                float4 e = *(const float4*)&Er[q * 4];
                float4 v;
                v.x = a.x + e.x; v.y = a.y + e.y; v.z = a.z + e.z; v.w = a.w + e.w;
                *(float4*)&sh[sp][k8 + q * 4] = v;
            }
        }
        __syncthreads();
#pragma unroll
        for (int k4 = 0; k4 < 32; k4 += 4) {
            float w[4][8];
#pragma unroll
            for (int kq = 0; kq < 4; ++kq) {
                float4 w0 = *(const float4*)&Ws[k4 + kq][tx * 4];
                float4 w1 = *(const float4*)&Ws[k4 + kq][128 + tx * 4];
                w[kq][0] = w0.x; w[kq][1] = w0.y; w[kq][2] = w0.z; w[kq][3] = w0.w;
                w[kq][4] = w1.x; w[kq][5] = w1.y; w[kq][6] = w1.z; w[kq][7] = w1.w;
            }
#pragma unroll
            for (int i = 0; i < 8; ++i) {
                float4 rv = *(const float4*)&sh[ty * 8 + i][k4];
                float rq[4] = {rv.x, rv.y, rv.z, rv.w};
#pragma unroll
                for (int kq = 0; kq < 4; ++kq)
#pragma unroll
                    for (int j = 0; j < 8; ++j)
                        acc[i][j] = fmaf(rq[kq], w[kq][j], acc[i][j]);
            }
        }
    }

    float bsec_r[8], wpred_r[8], injr[8];
#pragma unroll
    for (int j = 0; j < 8; ++j) {
        int c = (j < 4) ? (tx * 4 + j) : (128 + tx * 4 + j - 4);
        bsec_r[j] = bsec[c];
        wpred_r[j] = Wpred[c];
        injr[j] = injv[b * H + c];
    }
    const float bp = bpredg[0];
#pragma unroll
    for (int i = 0; i < 8; ++i) {
        int r = ty * 8 + i;
        float p = 0.f;
#pragma unroll
        for (int j = 0; j < 8; ++j) {
            float sec = acc[i][j] + bsec_r[j];
            p += fmaxf(injr[j] + sec, 0.f) * wpred_r[j];
        }
#pragma unroll
        for (int off = 16; off > 0; off >>= 1)
            p += __shfl_down(p, off, 32);
        if (tx == 0) {
            float logit = p + bp + tsc[r];
            float prob = (1.f / (1.f + expf(-logit))) * msk[r];
            out[b * KTOP + k0 + r] = prob;
        }
    }
}

// ---------------------------------------------------------------------------
extern "C" void kernel_launch(void* const* d_in, const int* in_sizes, int n_in,
                              void* d_out, int out_size, void* d_ws, size_t ws_size,
                              hipStream_t stream) {
    const float* inputs  = (const float*)d_in[0];
    const int*   imask   = (const int*)d_in[1];
    const float* tie     = (const float*)d_in[2];
    const float* W_start = (const float*)d_in[3];
    const float* b_start = (const float*)d_in[4];
    const float* W_end   = (const float*)d_in[5];
    const float* b_end   = (const float*)d_in[6];
    const float* W_s1    = (const float*)d_in[7];
    const float* b_s1    = (const float*)d_in[8];
    const float* W_s2    = (const float*)d_in[9];
    const float* b_s2    = (const float*)d_in[10];
    const float* W_inj   = (const float*)d_in[11];
    const float* b_inj   = (const float*)d_in[12];
    const float* W_sec   = (const float*)d_in[13];
    const float* b_sec   = (const float*)d_in[14];
    const float* W_pred  = (const float*)d_in[15];
    const float* b_pred  = (const float*)d_in[16];
    float* out = (float*)d_out;

    float* AE         = (float*)d_ws;
    float* scores     = AE + (size_t)BB * T * 512;
    int*   s_idx      = (int*)(scores + (size_t)BB * NSPAN);
    int*   e_idx      = s_idx + NSPAN;
    int*   top_idx    = e_idx + NSPAN;
    float* top_scores = (float*)(top_idx + BB * KTOP);
    float* injv       = top_scores + BB * KTOP;
    unsigned short* Wpk = (unsigned short*)(injv + BB * H);
    int*   shortlist  = (int*)(Wpk + 65536);
    int*   slcnt      = shortlist + BB * SCAP;

    prep_proj_kernel<<<577, 256, 0, stream>>>(inputs, W_start, b_start, W_end, b_end, AE,
                                              s_idx, e_idx, W_s1, Wpk,
                                              tie, W_inj, b_inj, injv);
    approx_kernel<<<512, 512, 0, stream>>>(AE, Wpk, b_s1, W_s2, b_s2,
                                           s_idx, e_idx, imask, scores);
    select_kernel<<<BB, 1024, 0, stream>>>(scores, shortlist, slcnt);
    exact_kernel<<<dim3(16, BB), 512, 0, stream>>>(AE, W_s1, b_s1, W_s2, b_s2,
                                                   s_idx, e_idx, shortlist, slcnt, scores);
    topk_kernel<<<BB, 1024, 0, stream>>>(scores, shortlist, slcnt, top_idx, top_scores);
    final_kernel<<<BB * 4, 256, 0, stream>>>(AE, s_idx, e_idx, imask, top_idx, top_scores,
                                             injv, W_sec, b_sec, W_pred, b_pred, out);
}